// Round 9
// baseline (276.772 us; speedup 1.0000x reference)
//
#include <hip/hip_runtime.h>
#include <hip/hip_bf16.h>
#include <stdint.h>

#define B_ 8
#define N_ 256
#define M_ 128
#define D_ 128

typedef __attribute__((ext_vector_type(8))) short short8;
typedef __attribute__((ext_vector_type(4))) short short4v;
typedef __attribute__((ext_vector_type(4))) float f32x4;

static __device__ __forceinline__ unsigned short f2bf(float x) {
    union { float f; unsigned int u; } c; c.f = x;
    unsigned int r = (c.u + 0x7FFFu + ((c.u >> 16) & 1u)) >> 16;
    return (unsigned short)r;
}
static __device__ __forceinline__ unsigned short bfhu(float x) {
    union { float f; unsigned int u; } c; c.f = x;
    return (unsigned short)((c.u + 0x8000u) >> 16);
}
static __device__ __forceinline__ unsigned int pkhu(float a, float b) {
    union { float f; unsigned int u; } ca, cb; ca.f = a; cb.f = b;
    return ((ca.u + 0x8000u) >> 16) | ((cb.u + 0x8000u) & 0xFFFF0000u);
}
static __device__ __forceinline__ float4 mul4(float4 a, float4 b) {
    return make_float4(a.x * b.x, a.y * b.y, a.z * b.z, a.w * b.w);
}
static __device__ __forceinline__ short8 pack8(float4 a, float4 b) {
    return (short8){(short)f2bf(a.x), (short)f2bf(a.y), (short)f2bf(a.z), (short)f2bf(a.w),
                    (short)f2bf(b.x), (short)f2bf(b.y), (short)f2bf(b.z), (short)f2bf(b.w)};
}

// ---------------- K0a: weight transposes (fp32) + wfrag (bf16, frag order) ---
__global__ void k0a_prep(const float* __restrict__ lin2_w, const float* __restrict__ lin3_w,
                         const float* __restrict__ mlp_w1, const float* __restrict__ mlp_w2,
                         const float* __restrict__ linv1_w, const float* __restrict__ linv2_w,
                         const float* __restrict__ linv3_w,
                         float* __restrict__ wT2, float* __restrict__ wT3,
                         float* __restrict__ wTm1, float* __restrict__ wTm2,
                         unsigned short* __restrict__ wfrag) {
    int gid = blockIdx.x * 256 + threadIdx.x;
    int task = gid >> 14;
    int idx = gid & 16383;
    if (task < 4) {
        int e = idx & 127, dd = idx >> 7;
        const float* src = task == 0 ? lin2_w : task == 1 ? lin3_w : task == 2 ? mlp_w1 : mlp_w2;
        float* dst = task == 0 ? wT2 : task == 1 ? wT3 : task == 2 ? wTm1 : wTm2;
        dst[dd * 128 + e] = src[e * 128 + dd];
    } else {
        int mat = task - 4;
        const float* src = mat == 0 ? linv1_w : mat == 1 ? linv2_w : linv3_w;
        int e = idx >> 7, k = idx & 127;
        int dst = ((((e >> 4) * 12 + (mat * 4 + (k >> 5))) * 4 + ((k >> 3) & 3)) * 16 + (e & 15)) * 8
                  + (k & 7);
        wfrag[dst] = f2bf(src[idx] * (1.0f / 3.0f));
    }
}

// ---------------- K0b: s_v2t[b,d] = sum_m gv2[b,m,m,d] ------------------------
__global__ void k0b_trace(const float* __restrict__ gv2, float* __restrict__ s_v2t) {
    int b = blockIdx.x, d = threadIdx.x;
    const float* p = gv2 + (size_t)b * (M_ * M_ * D_) + d;
    float acc = 0.f;
    #pragma unroll 8
    for (int m = 0; m < 128; ++m) acc += p[(size_t)m * 16512];
    s_v2t[b * 128 + d] = acc;
}

// ---------------- K0c: g1[b,e] = (lin1(s_v2t)+b1)*gs --------------------------
__global__ void k0c_g1(const float* __restrict__ s_v2t, const float* __restrict__ lin1_w,
                       const float* __restrict__ lin1_b, const float* __restrict__ gs,
                       float* __restrict__ g1) {
    __shared__ float sv[128];
    int b = blockIdx.x, e = threadIdx.x;
    sv[e] = s_v2t[b * 128 + e];
    __syncthreads();
    const float* w = lin1_w + e * 128;
    float acc = 0.f;
    #pragma unroll 4
    for (int dd = 0; dd < 128; ++dd) acc = fmaf(sv[dd], w[dd], acc);
    g1[b * 128 + e] = (acc + lin1_b[e]) * gs[b * 128 + e];
}

// ---------------- KT_v: vT (d-major bf16) + optional vgs = bf16(gs*v) ---------
__global__ __launch_bounds__(256) void kt_v(const float* __restrict__ v,
                                            const float* __restrict__ gs,
                                            unsigned short* __restrict__ vT,
                                            unsigned short* __restrict__ vgs) {
    __shared__ unsigned short tl[128 * 136];
    int bid = blockIdx.x;
    int b = bid >> 8;
    int R0 = (bid & 255) * 128;
    int t = threadIdx.x;
    int slot = t & 31;
    const float* src = v + ((size_t)b * 32768 + R0) * 128;
    float4 gs4 = *(const float4*)(gs + b * 128 + slot * 4);
    #pragma unroll
    for (int i = 0; i < 16; ++i) {
        int flat = i * 256 + t;
        int row = flat >> 5;
        float4 x = *(const float4*)(src + (size_t)row * 128 + slot * 4);
        #pragma unroll
        for (int j = 0; j < 4; ++j) {
            int d = slot * 4 + j;
            tl[d * 136 + (row ^ (((d >> 2) & 7) << 3))] = bfhu(((const float*)&x)[j]);
        }
        if (vgs) {
            uint2 pg = make_uint2(pkhu(x.x * gs4.x, x.y * gs4.y),
                                  pkhu(x.z * gs4.z, x.w * gs4.w));
            *(uint2*)(vgs + ((size_t)b * 32768 + R0 + row) * 128 + slot * 4) = pg;
        }
    }
    __syncthreads();
    #pragma unroll
    for (int i = 0; i < 8; ++i) {
        int flat = i * 256 + t;
        int d = flat >> 4, rs = flat & 15;
        short8 y = *(const short8*)&tl[d * 136 + ((rs * 8) ^ (((d >> 2) & 7) << 3))];
        *(short8*)(vT + (size_t)(b * 128 + d) * 32768 + R0 + rs * 8) = y;
    }
}

// ---------------- KT_g: gT[b,d,c,m] = bf16(gv2[b,m,c,d]) ----------------------
__global__ __launch_bounds__(256) void kt_g(const float* __restrict__ gv2,
                                            unsigned short* __restrict__ gT) {
    __shared__ unsigned short tl[128 * 136];
    int bid = blockIdx.x;
    int b = bid >> 7;
    int c = bid & 127;
    int t = threadIdx.x;
    const float* src = gv2 + ((size_t)(b * 128) * 128 + c) * 128;
    #pragma unroll
    for (int i = 0; i < 16; ++i) {
        int flat = i * 256 + t;
        int m = flat >> 5, slot = flat & 31;
        float4 x = *(const float4*)(src + (size_t)m * 16384 + slot * 4);
        #pragma unroll
        for (int j = 0; j < 4; ++j) {
            int d = slot * 4 + j;
            tl[d * 136 + (m ^ (((d >> 2) & 7) << 3))] = bfhu(((const float*)&x)[j]);
        }
    }
    __syncthreads();
    #pragma unroll
    for (int i = 0; i < 8; ++i) {
        int flat = i * 256 + t;
        int d = flat >> 4, ms = flat & 15;
        short8 y = *(const short8*)&tl[d * 136 + ((ms * 8) ^ (((d >> 2) & 7) << 3))];
        *(short8*)(gT + ((size_t)(b * 128 + d) * 128 + c) * 128 + ms * 8) = y;
    }
}

// ---------------- K1fast: T2 GEMM from pre-transposed bf16 inputs -------------
__global__ __launch_bounds__(512, 2) void k1_T2_fast(const unsigned short* __restrict__ vT,
                                                     const unsigned short* __restrict__ gT,
                                                     unsigned short* __restrict__ t2base) {
    __shared__ unsigned short sm[40960];
    int bid = blockIdx.x;
    int b = bid & 7;
    int r = bid >> 3;
    int nt = r & 3, ch = (r >> 2) & 1, dc = r >> 3;
    int n0 = nt * 64, c0 = ch * 64, d0 = dc * 8;
    int t = threadIdx.x;
    int w = t >> 6, lane = t & 63, ln15 = lane & 15, kg = lane >> 4;

    f32x4 acc[4][4];
    #pragma unroll
    for (int i = 0; i < 4; ++i)
        #pragma unroll
        for (int j = 0; j < 4; ++j) acc[i][j] = (f32x4){0.f, 0.f, 0.f, 0.f};

    for (int mc = 0; mc < 4; ++mc) {
        int m0 = mc * 32;
        #pragma unroll
        for (int i = 0; i < 4; ++i) {
            int flat = i * 512 + t;
            int d = flat >> 8, x = (flat >> 2) & 63, ms = flat & 3;
            short8 a = *(const short8*)(vT + ((size_t)(b * 128 + d0 + d) * 256 + n0 + x) * 128
                                           + m0 + ms * 8);
            *(short8*)&sm[d * 2560 + x * 40 + ms * 8] = a;
            short8 g = *(const short8*)(gT + ((size_t)(b * 128 + d0 + d) * 128 + c0 + x) * 128
                                           + m0 + ms * 8);
            *(short8*)&sm[20480 + d * 2560 + x * 40 + ms * 8] = g;
        }
        __syncthreads();
        short8 af[4], bf[4];
        #pragma unroll
        for (int i = 0; i < 4; ++i)
            af[i] = *(const short8*)&sm[w * 2560 + (i * 16 + ln15) * 40 + kg * 8];
        #pragma unroll
        for (int j = 0; j < 4; ++j)
            bf[j] = *(const short8*)&sm[20480 + w * 2560 + (j * 16 + ln15) * 40 + kg * 8];
        #pragma unroll
        for (int i = 0; i < 4; ++i)
            #pragma unroll
            for (int j = 0; j < 4; ++j)
                acc[i][j] = __builtin_amdgcn_mfma_f32_16x16x32_bf16(af[i], bf[j], acc[i][j], 0, 0, 0);
        __syncthreads();
    }
    #pragma unroll
    for (int i = 0; i < 4; ++i)
        #pragma unroll
        for (int j = 0; j < 4; ++j)
            #pragma unroll
            for (int q = 0; q < 4; ++q) {
                int n = i * 16 + kg * 4 + q;
                int c = j * 16 + ln15;
                sm[n * 520 + c * 8 + w] = bfhu(acc[i][j][q]);
            }
    __syncthreads();
    #pragma unroll
    for (int p = 0; p < 8; ++p) {
        int u = p * 512 + t;
        int n = u >> 6;
        int c = u & 63;
        short8 x = *(const short8*)&sm[n * 520 + c * 8];
        size_t kb = (size_t)(b * N_ + n0 + n) * 2 + ch;
        *(short8*)(t2base + kb * 16384 + (size_t)((c >> 4) * 16 + dc) * 128 + (c & 15) * 8) = x;
    }
}

// ---------------- K1 legacy (fallback) ----------------------------------------
__global__ __launch_bounds__(512, 4) void k1_T2_legacy(const float* __restrict__ v,
                                                       const float* __restrict__ gv2,
                                                       unsigned short* __restrict__ t2base) {
    __shared__ unsigned short sm[40960];
    int bid = blockIdx.x;
    int b = bid & 7;
    int r = bid >> 3;
    int nt = r & 3, ch = (r >> 2) & 1, dc = r >> 3;
    int n0 = nt * 64, c0 = ch * 64, d0 = dc * 8;
    int t = threadIdx.x;
    int w = t >> 6, lane = t & 63, ln15 = lane & 15, kg = lane >> 4;

    f32x4 acc[4][4];
    #pragma unroll
    for (int i = 0; i < 4; ++i)
        #pragma unroll
        for (int j = 0; j < 4; ++j) acc[i][j] = (f32x4){0.f, 0.f, 0.f, 0.f};

    int d0l = (t & 1) * 4;
    int am = (t >> 1) & 31, anb = t >> 6;
    int bc = (t >> 1) & 63, bmb = t >> 7;

    for (int mc = 0; mc < 4; ++mc) {
        int m0 = mc * 32;
        {
            const float* src = v + (((size_t)(b * N_ + n0) * M_ + m0 + am) * D_ + d0 + d0l);
            #pragma unroll
            for (int p = 0; p < 8; ++p) {
                int n = p * 8 + anb;
                float4 x = *(const float4*)(src + (size_t)n * (M_ * D_));
                #pragma unroll
                for (int j = 0; j < 4; ++j)
                    sm[(d0l + j) * 2560 + n * 40 + am] = f2bf(((const float*)&x)[j]);
            }
        }
        {
            const float* src = gv2 + (((size_t)(b * M_ + m0) * M_ + c0 + bc) * D_ + d0 + d0l);
            #pragma unroll
            for (int p = 0; p < 8; ++p) {
                int m = p * 4 + bmb;
                float4 x = *(const float4*)(src + (size_t)m * (M_ * D_));
                #pragma unroll
                for (int j = 0; j < 4; ++j)
                    sm[20480 + (d0l + j) * 2560 + bc * 40 + m] = f2bf(((const float*)&x)[j]);
            }
        }
        __syncthreads();
        short8 af[4], bf[4];
        #pragma unroll
        for (int i = 0; i < 4; ++i)
            af[i] = *(const short8*)&sm[w * 2560 + (i * 16 + ln15) * 40 + kg * 8];
        #pragma unroll
        for (int j = 0; j < 4; ++j)
            bf[j] = *(const short8*)&sm[20480 + w * 2560 + (j * 16 + ln15) * 40 + kg * 8];
        #pragma unroll
        for (int i = 0; i < 4; ++i)
            #pragma unroll
            for (int j = 0; j < 4; ++j)
                acc[i][j] = __builtin_amdgcn_mfma_f32_16x16x32_bf16(af[i], bf[j], acc[i][j], 0, 0, 0);
        __syncthreads();
    }
    #pragma unroll
    for (int i = 0; i < 4; ++i)
        #pragma unroll
        for (int j = 0; j < 4; ++j)
            #pragma unroll
            for (int q = 0; q < 4; ++q) {
                int n = i * 16 + kg * 4 + q;
                int c = j * 16 + ln15;
                sm[(n * 64 + c) * 8 + w] = f2bf(acc[i][j][q]);
            }
    __syncthreads();
    #pragma unroll
    for (int p = 0; p < 8; ++p) {
        int u = p * 512 + t;
        int n = u >> 6;
        int c = u & 63;
        short8 x = *(const short8*)&sm[(n * 64 + c) * 8];
        size_t kb = (size_t)(b * N_ + n0 + n) * 2 + ch;
        *(short8*)(t2base + kb * 16384 + (size_t)((c >> 4) * 16 + dc) * 128 + (c & 15) * 8) = x;
    }
}

// ---------------- K2p: persistent v_new GEMM (weights staged once/CU) ---------
// 256 blocks x 4 iterations x 2 rows; vgs (bf16, gs-premultiplied) replaces the
// f32 v read and half the pack VALU. MFMA core verbatim from verified R8.
__global__ __launch_bounds__(512, 1) void k2_vnew_p(
        const float* __restrict__ s, const unsigned short* __restrict__ vgs,
        const float* __restrict__ gv,
        const unsigned short* __restrict__ wfrag,
        float* __restrict__ vnew, float* __restrict__ svv) {
    __shared__ unsigned short smw[49152];
    __shared__ float part[2][4][128];
    int t = threadIdx.x;
    int w = t >> 6, sb = w >> 2, w4 = w & 3;
    int lane = t & 63, ln15 = lane & 15, kgrp = lane >> 4;

    #pragma unroll
    for (int r = 0; r < 12; ++r) {
        int idx = (r * 512 + t) * 8;
        *(short8*)&smw[idx] = *(const short8*)(wfrag + idx);
    }

    for (int j = 0; j < 4; ++j) {
        int pair = blockIdx.x + 256 * j;
        int kb2 = pair * 2 + sb;
        int b = kb2 >> 8;
        const unsigned short* t2u = (const unsigned short*)(vnew + (size_t)kb2 * 16384);
        short8 aT[2][4];
        #pragma unroll
        for (int h = 0; h < 2; ++h) {
            int rt = w4 * 2 + h;
            const unsigned short* tb = t2u + (rt >> 2) * 16384 + ((rt & 3) * 16 + kgrp) * 128
                                      + ln15 * 8;
            #pragma unroll
            for (int kk = 0; kk < 4; ++kk)
                aT[h][kk] = *(const short8*)(tb + kk * 512);
        }
        const float* srow = s + (size_t)kb2 * 128;
        float4 ss[8];
        #pragma unroll
        for (int kk = 0; kk < 4; ++kk) {
            int dd = kk * 32 + kgrp * 8;
            ss[kk * 2]     = *(const float4*)(srow + dd);
            ss[kk * 2 + 1] = *(const float4*)(srow + dd + 4);
        }
        __syncthreads();   // T2 reads drained (in-place hazard); smw ready (j=0)

        float psum[8] = {0.f, 0.f, 0.f, 0.f, 0.f, 0.f, 0.f, 0.f};
        #pragma unroll
        for (int h = 0; h < 2; ++h) {
            int rt = w4 * 2 + h;
            int ca = rt * 16 + ln15;
            const float* gvr = gv + ((size_t)b * M_ + ca) * D_;
            const unsigned short* vgr = vgs + ((size_t)kb2 * M_ + ca) * D_;
            short8 aD[8];
            #pragma unroll
            for (int kk = 0; kk < 4; ++kk) {
                int dd = kk * 32 + kgrp * 8;
                float4 g0 = *(const float4*)(gvr + dd), g1 = *(const float4*)(gvr + dd + 4);
                aD[kk]     = pack8(mul4(ss[kk * 2], g0), mul4(ss[kk * 2 + 1], g1));
                aD[4 + kk] = *(const short8*)(vgr + dd);
            }
            float* outp = vnew + (size_t)kb2 * 16384 + (rt >> 2) * 8192;
            int rowl = (rt & 3) * 16 + kgrp * 4;
            const float* grow = gv + ((size_t)b * M_ + rt * 16 + kgrp * 4) * D_;
            #pragma unroll
            for (int ct = 0; ct < 8; ++ct) {
                f32x4 acc = {0.f, 0.f, 0.f, 0.f};
                #pragma unroll
                for (int kk = 0; kk < 12; ++kk) {
                    short8 a = (kk < 4) ? aT[h][kk] : aD[kk - 4];
                    short8 bfr = *(const short8*)&smw[(((ct * 12 + kk) * 4 + kgrp) * 16 + ln15) * 8];
                    acc = __builtin_amdgcn_mfma_f32_16x16x32_bf16(a, bfr, acc, 0, 0, 0);
                }
                int e = ct * 16 + ln15;
                #pragma unroll
                for (int q = 0; q < 4; ++q) {
                    outp[(size_t)(rowl + q) * 128 + e] = acc[q];
                    psum[ct] = fmaf(grow[(size_t)q * 128 + e], acc[q], psum[ct]);
                }
            }
        }
        #pragma unroll
        for (int ct = 0; ct < 8; ++ct) {
            psum[ct] += __shfl_xor(psum[ct], 16);
            psum[ct] += __shfl_xor(psum[ct], 32);
        }
        if (kgrp == 0) {
            #pragma unroll
            for (int ct = 0; ct < 8; ++ct) part[sb][w4][ct * 16 + ln15] = psum[ct];
        }
        __syncthreads();
        int tl = t & 255, sb2 = t >> 8;
        if (tl < 128) {
            int kbo = pair * 2 + sb2;
            svv[(size_t)kbo * 128 + tl] =
                part[sb2][0][tl] + part[sb2][1][tl] + part[sb2][2][tl] + part[sb2][3][tl];
        }
    }
}

// ---------------- K2 (R8 fallback, reads v f32) -------------------------------
__global__ __launch_bounds__(512, 2) void k2_vnew(
        const float* __restrict__ s, const float* __restrict__ v,
        const float* __restrict__ gs, const float* __restrict__ gv,
        const unsigned short* __restrict__ wfrag,
        float* __restrict__ vnew, float* __restrict__ svv) {
    __shared__ unsigned short smw[49152];
    __shared__ float part[2][4][128];
    int t = threadIdx.x;
    int w = t >> 6;
    int sb = w >> 2;
    int w4 = w & 3;
    int kb2 = blockIdx.x * 2 + sb;
    int b = kb2 >> 8;
    int lane = t & 63, ln15 = lane & 15, kgrp = lane >> 4;

    #pragma unroll
    for (int r = 0; r < 12; ++r) {
        int idx = (r * 512 + t) * 8;
        *(short8*)&smw[idx] = *(const short8*)(wfrag + idx);
    }
    const unsigned short* t2u = (const unsigned short*)(vnew + (size_t)kb2 * 16384);
    short8 aT[2][4];
    #pragma unroll
    for (int h = 0; h < 2; ++h) {
        int rt = w4 * 2 + h;
        const unsigned short* tb = t2u + (rt >> 2) * 16384 + ((rt & 3) * 16 + kgrp) * 128 + ln15 * 8;
        #pragma unroll
        for (int kk = 0; kk < 4; ++kk)
            aT[h][kk] = *(const short8*)(tb + kk * 512);
    }
    const float* srow = s + (size_t)kb2 * 128;
    const float* gsr  = gs + (size_t)b * 128;
    float4 ss[8], qq[8];
    #pragma unroll
    for (int kk = 0; kk < 4; ++kk) {
        int dd = kk * 32 + kgrp * 8;
        ss[kk * 2]     = *(const float4*)(srow + dd);
        ss[kk * 2 + 1] = *(const float4*)(srow + dd + 4);
        qq[kk * 2]     = *(const float4*)(gsr + dd);
        qq[kk * 2 + 1] = *(const float4*)(gsr + dd + 4);
    }
    __syncthreads();

    float psum[8] = {0.f, 0.f, 0.f, 0.f, 0.f, 0.f, 0.f, 0.f};
    #pragma unroll
    for (int h = 0; h < 2; ++h) {
        int rt = w4 * 2 + h;
        int ca = rt * 16 + ln15;
        const float* gvr = gv + ((size_t)b * M_ + ca) * D_;
        const float* vr  = v + ((size_t)kb2 * M_ + ca) * D_;
        short8 aD[8];
        #pragma unroll
        for (int kk = 0; kk < 4; ++kk) {
            int dd = kk * 32 + kgrp * 8;
            float4 g0 = *(const float4*)(gvr + dd), g1 = *(const float4*)(gvr + dd + 4);
            float4 v0 = *(const float4*)(vr + dd),  v1 = *(const float4*)(vr + dd + 4);
            aD[kk]     = pack8(mul4(ss[kk * 2], g0), mul4(ss[kk * 2 + 1], g1));
            aD[4 + kk] = pack8(mul4(qq[kk * 2], v0), mul4(qq[kk * 2 + 1], v1));
        }
        float* outp = vnew + (size_t)kb2 * 16384 + (rt >> 2) * 8192;
        int rowl = (rt & 3) * 16 + kgrp * 4;
        const float* grow = gv + ((size_t)b * M_ + rt * 16 + kgrp * 4) * D_;
        #pragma unroll
        for (int ct = 0; ct < 8; ++ct) {
            f32x4 acc = {0.f, 0.f, 0.f, 0.f};
            #pragma unroll
            for (int kk = 0; kk < 12; ++kk) {
                short8 a = (kk < 4) ? aT[h][kk] : aD[kk - 4];
                short8 bfr = *(const short8*)&smw[(((ct * 12 + kk) * 4 + kgrp) * 16 + ln15) * 8];
                acc = __builtin_amdgcn_mfma_f32_16x16x32_bf16(a, bfr, acc, 0, 0, 0);
            }
            int e = ct * 16 + ln15;
            #pragma unroll
            for (int q = 0; q < 4; ++q) {
                outp[(size_t)(rowl + q) * 128 + e] = acc[q];
                psum[ct] = fmaf(grow[(size_t)q * 128 + e], acc[q], psum[ct]);
            }
        }
    }
    #pragma unroll
    for (int ct = 0; ct < 8; ++ct) {
        psum[ct] += __shfl_xor(psum[ct], 16);
        psum[ct] += __shfl_xor(psum[ct], 32);
    }
    if (kgrp == 0) {
        #pragma unroll
        for (int ct = 0; ct < 8; ++ct) part[sb][w4][ct * 16 + ln15] = psum[ct];
    }
    __syncthreads();
    int tl = t & 255;
    int sb2 = t >> 8;
    if (tl < 128) {
        int kbo = blockIdx.x * 2 + sb2;
        svv[(size_t)kbo * 128 + tl] =
            part[sb2][0][tl] + part[sb2][1][tl] + part[sb2][2][tl] + part[sb2][3][tl];
    }
}

// ---------------- K4: s-path linears + products + MLP -------------------------
__global__ __launch_bounds__(256) void k4_spath(
        const float* __restrict__ s, const float* __restrict__ svv,
        const float* __restrict__ g1,
        const float* __restrict__ wT2, const float* __restrict__ lin2_b,
        const float* __restrict__ wT3, const float* __restrict__ lin3_b,
        const float* __restrict__ wTm1, const float* __restrict__ mlp_b1,
        const float* __restrict__ wTm2, const float* __restrict__ mlp_b2,
        float* __restrict__ sout) {
    __shared__ float xs[8][128], xv[8][128], pre[8][128], hbuf[8][128];
    int t = threadIdx.x;
    int rowb = blockIdx.x * 8;
    int b = rowb >> 8;
    #pragma unroll
    for (int i = 0; i < 4; ++i) {
        int vi = i * 256 + t;
        int r = vi >> 7, dd = vi & 127;
        xs[r][dd] = s[(size_t)(rowb + r) * 128 + dd];
        xv[r][dd] = svv[(size_t)(rowb + r) * 128 + dd];
    }
    __syncthreads();
    int e = t & 127, h2 = t >> 7;
    float b2 = lin2_b[e], b3 = lin3_b[e], g1v = g1[b * 128 + e];
    float a2[4] = {b2, b2, b2, b2}, a3[4] = {b3, b3, b3, b3};
    for (int dd = 0; dd < 128; ++dd) {
        float w2 = wT2[dd * 128 + e], w3 = wT3[dd * 128 + e];
        #pragma unroll
        for (int r = 0; r < 4; ++r) {
            a2[r] = fmaf(xs[h2 * 4 + r][dd], w2, a2[r]);
            a3[r] = fmaf(xv[h2 * 4 + r][dd], w3, a3[r]);
        }
    }
    #pragma unroll
    for (int r = 0; r < 4; ++r) pre[h2 * 4 + r][e] = g1v * a2[r] * a3[r];
    __syncthreads();
    float bm1 = mlp_b1[e];
    float ah[4] = {bm1, bm1, bm1, bm1};
    for (int dd = 0; dd < 128; ++dd) {
        float w = wTm1[dd * 128 + e];
        #pragma unroll
        for (int r = 0; r < 4; ++r) ah[r] = fmaf(pre[h2 * 4 + r][dd], w, ah[r]);
    }
    #pragma unroll
    for (int r = 0; r < 4; ++r) hbuf[h2 * 4 + r][e] = fmaxf(ah[r], 0.f);
    __syncthreads();
    float bm2 = mlp_b2[e];
    float ao[4] = {bm2, bm2, bm2, bm2};
    for (int dd = 0; dd < 128; ++dd) {
        float w = wTm2[dd * 128 + e];
        #pragma unroll
        for (int r = 0; r < 4; ++r) ao[r] = fmaf(hbuf[h2 * 4 + r][dd], w, ao[r]);
    }
    #pragma unroll
    for (int r = 0; r < 4; ++r) sout[(size_t)(rowb + h2 * 4 + r) * 128 + e] = ao[r];
}

extern "C" void kernel_launch(void* const* d_in, const int* in_sizes, int n_in,
                              void* d_out, int out_size, void* d_ws, size_t ws_size,
                              hipStream_t stream) {
    const float* s       = (const float*)d_in[0];
    const float* v       = (const float*)d_in[1];
    const float* gs      = (const float*)d_in[2];
    const float* gv      = (const float*)d_in[3];
    const float* gv2     = (const float*)d_in[4];
    const float* lin1_w  = (const float*)d_in[5];
    const float* lin1_b  = (const float*)d_in[6];
    const float* lin2_w  = (const float*)d_in[7];
    const float* lin2_b  = (const float*)d_in[8];
    const float* lin3_w  = (const float*)d_in[9];
    const float* lin3_b  = (const float*)d_in[10];
    const float* linv1_w = (const float*)d_in[11];
    const float* linv2_w = (const float*)d_in[12];
    const float* linv3_w = (const float*)d_in[13];
    const float* mlp_w1  = (const float*)d_in[14];
    const float* mlp_b1  = (const float*)d_in[15];
    const float* mlp_w2  = (const float*)d_in[16];
    const float* mlp_b2  = (const float*)d_in[17];

    float* sout = (float*)d_out;
    float* vnew = (float*)d_out + 262144;   // v_new region; doubles as T2 (bf16)

    float* wsf   = (float*)d_ws;
    float* wT2   = wsf;
    float* wT3   = wsf + 16384;
    float* wTm1  = wsf + 32768;
    float* wTm2  = wsf + 49152;
    float* s_v2t = wsf + 65536;
    float* g1    = wsf + 66560;
    float* svv   = wsf + 67584;
    unsigned short* wfrag = (unsigned short*)(wsf + 329728);           // 96 KB
    unsigned short* vT  = (unsigned short*)((char*)d_ws + 2097152);    // 67.1 MB
    unsigned short* gT  = (unsigned short*)((char*)d_ws + 69206016);   // 33.5 MB
    unsigned short* vgs = (unsigned short*)((char*)d_ws + 102760448);  // 67.1 MB
    bool big  = ws_size >= 102760448ULL;
    bool huge = ws_size >= 169869312ULL;

    k0a_prep<<<448, 256, 0, stream>>>(lin2_w, lin3_w, mlp_w1, mlp_w2,
                                      linv1_w, linv2_w, linv3_w,
                                      wT2, wT3, wTm1, wTm2, wfrag);
    k0b_trace<<<8, 128, 0, stream>>>(gv2, s_v2t);
    k0c_g1<<<8, 128, 0, stream>>>(s_v2t, lin1_w, lin1_b, gs, g1);
    if (big) {
        kt_v<<<2048, 256, 0, stream>>>(v, gs, vT, huge ? vgs : (unsigned short*)nullptr);
        kt_g<<<1024, 256, 0, stream>>>(gv2, gT);
        k1_T2_fast<<<1024, 512, 0, stream>>>(vT, gT, (unsigned short*)vnew);
    } else {
        k1_T2_legacy<<<1024, 512, 0, stream>>>(v, gv2, (unsigned short*)vnew);
    }
    if (huge) {
        k2_vnew_p<<<256, 512, 0, stream>>>(s, vgs, gv, wfrag, vnew, svv);
    } else {
        k2_vnew<<<1024, 512, 0, stream>>>(s, v, gs, gv, wfrag, vnew, svv);
    }
    k4_spath<<<256, 256, 0, stream>>>(s, svv, g1, wT2, lin2_b, wT3, lin3_b,
                                      wTm1, mlp_b1, wTm2, mlp_b2, sout);
}

// Round 10
// 258.933 us; speedup vs baseline: 1.0689x; 1.0689x over previous
//
#include <hip/hip_runtime.h>
#include <hip/hip_bf16.h>
#include <stdint.h>

#define B_ 8
#define N_ 256
#define M_ 128
#define D_ 128

typedef __attribute__((ext_vector_type(8))) short short8;
typedef __attribute__((ext_vector_type(4))) short short4v;
typedef __attribute__((ext_vector_type(4))) float f32x4;

static __device__ __forceinline__ unsigned short f2bf(float x) {
    union { float f; unsigned int u; } c; c.f = x;
    unsigned int r = (c.u + 0x7FFFu + ((c.u >> 16) & 1u)) >> 16;
    return (unsigned short)r;
}
static __device__ __forceinline__ unsigned short bfhu(float x) {
    union { float f; unsigned int u; } c; c.f = x;
    return (unsigned short)((c.u + 0x8000u) >> 16);
}
static __device__ __forceinline__ unsigned int pkhu(float a, float b) {
    union { float f; unsigned int u; } ca, cb; ca.f = a; cb.f = b;
    return ((ca.u + 0x8000u) >> 16) | ((cb.u + 0x8000u) & 0xFFFF0000u);
}

// ---------------- K0a: weight transposes (fp32) + wfrag (bf16, frag order) ---
__global__ void k0a_prep(const float* __restrict__ lin2_w, const float* __restrict__ lin3_w,
                         const float* __restrict__ mlp_w1, const float* __restrict__ mlp_w2,
                         const float* __restrict__ linv1_w, const float* __restrict__ linv2_w,
                         const float* __restrict__ linv3_w,
                         float* __restrict__ wT2, float* __restrict__ wT3,
                         float* __restrict__ wTm1, float* __restrict__ wTm2,
                         unsigned short* __restrict__ wfrag) {
    int gid = blockIdx.x * 256 + threadIdx.x;
    int task = gid >> 14;
    int idx = gid & 16383;
    if (task < 4) {
        int e = idx & 127, dd = idx >> 7;
        const float* src = task == 0 ? lin2_w : task == 1 ? lin3_w : task == 2 ? mlp_w1 : mlp_w2;
        float* dst = task == 0 ? wT2 : task == 1 ? wT3 : task == 2 ? wTm1 : wTm2;
        dst[dd * 128 + e] = src[e * 128 + dd];
    } else {
        int mat = task - 4;
        const float* src = mat == 0 ? linv1_w : mat == 1 ? linv2_w : linv3_w;
        int e = idx >> 7, k = idx & 127;
        int dst = ((((e >> 4) * 12 + (mat * 4 + (k >> 5))) * 4 + ((k >> 3) & 3)) * 16 + (e & 15)) * 8
                  + (k & 7);
        wfrag[dst] = f2bf(src[idx] * (1.0f / 3.0f));
    }
}

// ---------------- K0b: s_v2t[b,d] = sum_m gv2[b,m,m,d] ------------------------
__global__ void k0b_trace(const float* __restrict__ gv2, float* __restrict__ s_v2t) {
    int b = blockIdx.x, d = threadIdx.x;
    const float* p = gv2 + (size_t)b * (M_ * M_ * D_) + d;
    float acc = 0.f;
    #pragma unroll 8
    for (int m = 0; m < 128; ++m) acc += p[(size_t)m * 16512];
    s_v2t[b * 128 + d] = acc;
}

// ---------------- K0c: g1[b,e] = (lin1(s_v2t)+b1)*gs --------------------------
__global__ void k0c_g1(const float* __restrict__ s_v2t, const float* __restrict__ lin1_w,
                       const float* __restrict__ lin1_b, const float* __restrict__ gs,
                       float* __restrict__ g1) {
    __shared__ float sv[128];
    int b = blockIdx.x, e = threadIdx.x;
    sv[e] = s_v2t[b * 128 + e];
    __syncthreads();
    const float* w = lin1_w + e * 128;
    float acc = 0.f;
    #pragma unroll 4
    for (int dd = 0; dd < 128; ++dd) acc = fmaf(sv[dd], w[dd], acc);
    g1[b * 128 + e] = (acc + lin1_b[e]) * gs[b * 128 + e];
}

// ---------------- KT_v: vT[b,d,n*M+m] = bf16(v[b,n,m,d]) (R8-verified) --------
__global__ __launch_bounds__(256) void kt_v(const float* __restrict__ v,
                                            unsigned short* __restrict__ vT) {
    __shared__ unsigned short tl[128 * 136];
    int bid = blockIdx.x;
    int b = bid >> 8;
    int R0 = (bid & 255) * 128;
    int t = threadIdx.x;
    const float* src = v + ((size_t)b * 32768 + R0) * 128;
    #pragma unroll
    for (int i = 0; i < 16; ++i) {
        int flat = i * 256 + t;
        int row = flat >> 5, slot = flat & 31;
        float4 x = *(const float4*)(src + (size_t)row * 128 + slot * 4);
        #pragma unroll
        for (int j = 0; j < 4; ++j) {
            int d = slot * 4 + j;
            tl[d * 136 + (row ^ (((d >> 2) & 7) << 3))] = bfhu(((const float*)&x)[j]);
        }
    }
    __syncthreads();
    #pragma unroll
    for (int i = 0; i < 8; ++i) {
        int flat = i * 256 + t;
        int d = flat >> 4, rs = flat & 15;
        short8 y = *(const short8*)&tl[d * 136 + ((rs * 8) ^ (((d >> 2) & 7) << 3))];
        *(short8*)(vT + (size_t)(b * 128 + d) * 32768 + R0 + rs * 8) = y;
    }
}

// ---------------- KT_g: gT[b,d,c,m] = bf16(gv2[b,m,c,d]) ----------------------
__global__ __launch_bounds__(256) void kt_g(const float* __restrict__ gv2,
                                            unsigned short* __restrict__ gT) {
    __shared__ unsigned short tl[128 * 136];
    int bid = blockIdx.x;
    int b = bid >> 7;
    int c = bid & 127;
    int t = threadIdx.x;
    const float* src = gv2 + ((size_t)(b * 128) * 128 + c) * 128;
    #pragma unroll
    for (int i = 0; i < 16; ++i) {
        int flat = i * 256 + t;
        int m = flat >> 5, slot = flat & 31;
        float4 x = *(const float4*)(src + (size_t)m * 16384 + slot * 4);
        #pragma unroll
        for (int j = 0; j < 4; ++j) {
            int d = slot * 4 + j;
            tl[d * 136 + (m ^ (((d >> 2) & 7) << 3))] = bfhu(((const float*)&x)[j]);
        }
    }
    __syncthreads();
    #pragma unroll
    for (int i = 0; i < 8; ++i) {
        int flat = i * 256 + t;
        int d = flat >> 4, ms = flat & 15;
        short8 y = *(const short8*)&tl[d * 136 + ((ms * 8) ^ (((d >> 2) & 7) << 3))];
        *(short8*)(gT + ((size_t)(b * 128 + d) * 128 + c) * 128 + ms * 8) = y;
    }
}

// ---------------- K1fast: T2 GEMM from pre-transposed bf16 inputs -------------
__global__ __launch_bounds__(512, 2) void k1_T2_fast(const unsigned short* __restrict__ vT,
                                                     const unsigned short* __restrict__ gT,
                                                     unsigned short* __restrict__ t2base) {
    __shared__ unsigned short sm[40960];
    int bid = blockIdx.x;
    int b = bid & 7;
    int r = bid >> 3;
    int nt = r & 3, ch = (r >> 2) & 1, dc = r >> 3;
    int n0 = nt * 64, c0 = ch * 64, d0 = dc * 8;
    int t = threadIdx.x;
    int w = t >> 6, lane = t & 63, ln15 = lane & 15, kg = lane >> 4;

    f32x4 acc[4][4];
    #pragma unroll
    for (int i = 0; i < 4; ++i)
        #pragma unroll
        for (int j = 0; j < 4; ++j) acc[i][j] = (f32x4){0.f, 0.f, 0.f, 0.f};

    for (int mc = 0; mc < 4; ++mc) {
        int m0 = mc * 32;
        #pragma unroll
        for (int i = 0; i < 4; ++i) {
            int flat = i * 512 + t;
            int d = flat >> 8, x = (flat >> 2) & 63, ms = flat & 3;
            short8 a = *(const short8*)(vT + ((size_t)(b * 128 + d0 + d) * 256 + n0 + x) * 128
                                           + m0 + ms * 8);
            *(short8*)&sm[d * 2560 + x * 40 + ms * 8] = a;
            short8 g = *(const short8*)(gT + ((size_t)(b * 128 + d0 + d) * 128 + c0 + x) * 128
                                           + m0 + ms * 8);
            *(short8*)&sm[20480 + d * 2560 + x * 40 + ms * 8] = g;
        }
        __syncthreads();
        short8 af[4], bf[4];
        #pragma unroll
        for (int i = 0; i < 4; ++i)
            af[i] = *(const short8*)&sm[w * 2560 + (i * 16 + ln15) * 40 + kg * 8];
        #pragma unroll
        for (int j = 0; j < 4; ++j)
            bf[j] = *(const short8*)&sm[20480 + w * 2560 + (j * 16 + ln15) * 40 + kg * 8];
        #pragma unroll
        for (int i = 0; i < 4; ++i)
            #pragma unroll
            for (int j = 0; j < 4; ++j)
                acc[i][j] = __builtin_amdgcn_mfma_f32_16x16x32_bf16(af[i], bf[j], acc[i][j], 0, 0, 0);
        __syncthreads();
    }
    #pragma unroll
    for (int i = 0; i < 4; ++i)
        #pragma unroll
        for (int j = 0; j < 4; ++j)
            #pragma unroll
            for (int q = 0; q < 4; ++q) {
                int n = i * 16 + kg * 4 + q;
                int c = j * 16 + ln15;
                sm[n * 520 + c * 8 + w] = bfhu(acc[i][j][q]);
            }
    __syncthreads();
    #pragma unroll
    for (int p = 0; p < 8; ++p) {
        int u = p * 512 + t;
        int n = u >> 6;
        int c = u & 63;
        short8 x = *(const short8*)&sm[n * 520 + c * 8];
        size_t kb = (size_t)(b * N_ + n0 + n) * 2 + ch;
        *(short8*)(t2base + kb * 16384 + (size_t)((c >> 4) * 16 + dc) * 128 + (c & 15) * 8) = x;
    }
}

// ---------------- K1 legacy (fallback) ----------------------------------------
__global__ __launch_bounds__(512, 4) void k1_T2_legacy(const float* __restrict__ v,
                                                       const float* __restrict__ gv2,
                                                       unsigned short* __restrict__ t2base) {
    __shared__ unsigned short sm[40960];
    int bid = blockIdx.x;
    int b = bid & 7;
    int r = bid >> 3;
    int nt = r & 3, ch = (r >> 2) & 1, dc = r >> 3;
    int n0 = nt * 64, c0 = ch * 64, d0 = dc * 8;
    int t = threadIdx.x;
    int w = t >> 6, lane = t & 63, ln15 = lane & 15, kg = lane >> 4;

    f32x4 acc[4][4];
    #pragma unroll
    for (int i = 0; i < 4; ++i)
        #pragma unroll
        for (int j = 0; j < 4; ++j) acc[i][j] = (f32x4){0.f, 0.f, 0.f, 0.f};

    int d0l = (t & 1) * 4;
    int am = (t >> 1) & 31, anb = t >> 6;
    int bc = (t >> 1) & 63, bmb = t >> 7;

    for (int mc = 0; mc < 4; ++mc) {
        int m0 = mc * 32;
        {
            const float* src = v + (((size_t)(b * N_ + n0) * M_ + m0 + am) * D_ + d0 + d0l);
            #pragma unroll
            for (int p = 0; p < 8; ++p) {
                int n = p * 8 + anb;
                float4 x = *(const float4*)(src + (size_t)n * (M_ * D_));
                #pragma unroll
                for (int j = 0; j < 4; ++j)
                    sm[(d0l + j) * 2560 + n * 40 + am] = f2bf(((const float*)&x)[j]);
            }
        }
        {
            const float* src = gv2 + (((size_t)(b * M_ + m0) * M_ + c0 + bc) * D_ + d0 + d0l);
            #pragma unroll
            for (int p = 0; p < 8; ++p) {
                int m = p * 4 + bmb;
                float4 x = *(const float4*)(src + (size_t)m * (M_ * D_));
                #pragma unroll
                for (int j = 0; j < 4; ++j)
                    sm[20480 + (d0l + j) * 2560 + bc * 40 + m] = f2bf(((const float*)&x)[j]);
            }
        }
        __syncthreads();
        short8 af[4], bf[4];
        #pragma unroll
        for (int i = 0; i < 4; ++i)
            af[i] = *(const short8*)&sm[w * 2560 + (i * 16 + ln15) * 40 + kg * 8];
        #pragma unroll
        for (int j = 0; j < 4; ++j)
            bf[j] = *(const short8*)&sm[20480 + w * 2560 + (j * 16 + ln15) * 40 + kg * 8];
        #pragma unroll
        for (int i = 0; i < 4; ++i)
            #pragma unroll
            for (int j = 0; j < 4; ++j)
                acc[i][j] = __builtin_amdgcn_mfma_f32_16x16x32_bf16(af[i], bf[j], acc[i][j], 0, 0, 0);
        __syncthreads();
    }
    #pragma unroll
    for (int i = 0; i < 4; ++i)
        #pragma unroll
        for (int j = 0; j < 4; ++j)
            #pragma unroll
            for (int q = 0; q < 4; ++q) {
                int n = i * 16 + kg * 4 + q;
                int c = j * 16 + ln15;
                sm[(n * 64 + c) * 8 + w] = f2bf(acc[i][j][q]);
            }
    __syncthreads();
    #pragma unroll
    for (int p = 0; p < 8; ++p) {
        int u = p * 512 + t;
        int n = u >> 6;
        int c = u & 63;
        short8 x = *(const short8*)&sm[(n * 64 + c) * 8];
        size_t kb = (size_t)(b * N_ + n0 + n) * 2 + ch;
        *(short8*)(t2base + kb * 16384 + (size_t)((c >> 4) * 16 + dc) * 128 + (c & 15) * 8) = x;
    }
}

// ---------------- K2w: v_new GEMM — weights in REGISTERS, A-tile in 12KB LDS --
// Block = one (b,n); 8 waves, wave w owns e-tile ct=w (12 B-frags = 48 VGPR,
// pinned). Per rt (16 c-rows): 512 threads stage A [12][4][16][8] (T2 chunk =
// 4KB linear copy; s*gv, gs*v computed from coalesced f32 rows), 2 barriers,
// 12 ds_read_b128 + 12 MFMA per wave. rt order {2,3,1,0,6,7,5,4} guarantees
// every T2 chunk is staged before any overlapping output row is written.
// s_vv fused per-wave (scalar psum + shfl over kgrp).
__global__ __launch_bounds__(512, 4) void k2_vnew_w(
        const float* __restrict__ s, const float* __restrict__ v,
        const float* __restrict__ gs, const float* __restrict__ gv,
        const unsigned short* __restrict__ wfrag,
        float* __restrict__ vnew, float* __restrict__ svv) {
    __shared__ unsigned short lds_a[6144];
    int t = threadIdx.x;
    int kb2 = blockIdx.x;              // b*256 + n
    int b = kb2 >> 8;
    int w = t >> 6, lane = t & 63, ln15 = lane & 15, kgrp = lane >> 4;
    int ct = w;

    // register-resident weight fragments for this wave's e-tile (pinned)
    f32x4 wreg[12];
    #pragma unroll
    for (int kk = 0; kk < 12; ++kk)
        wreg[kk] = *(const f32x4*)&wfrag[(((ct * 12 + kk) * 4 + kgrp) * 16 + ln15) * 8];
    asm volatile("" : "+v"(wreg[0]), "+v"(wreg[1]), "+v"(wreg[2]), "+v"(wreg[3]),
                      "+v"(wreg[4]), "+v"(wreg[5]), "+v"(wreg[6]), "+v"(wreg[7]),
                      "+v"(wreg[8]), "+v"(wreg[9]), "+v"(wreg[10]), "+v"(wreg[11]));

    // staging-role constants (thread -> (row r_s, dd-quad q5))
    int r_s = t >> 5;
    int q5 = t & 31;
    int dd0 = q5 * 4;
    float4 s4  = *(const float4*)(s + (size_t)kb2 * 128 + dd0);
    float4 gs4 = *(const float4*)(gs + (size_t)b * 128 + dd0);
    const float* gvb = gv + (size_t)b * 16384;
    const unsigned short* t2u = (const unsigned short*)(vnew + (size_t)kb2 * 16384);
    float* outp = vnew + (size_t)kb2 * 16384;
    int lw = 2048 + (q5 >> 3) * 512 + ((q5 >> 1) & 3) * 128 + r_s * 8 + (q5 & 1) * 4;

    float psum = 0.f;
    #pragma unroll
    for (int j = 0; j < 8; ++j) {
        int rt = (0x45760132u >> (4 * j)) & 7;   // {2,3,1,0,6,7,5,4}
        int crow = (rt >> 2) * 64 + (rt & 3) * 16;
        // ---- stage A-tile ----
        if (t < 256) {
            short8 x = *(const short8*)(t2u + (rt >> 2) * 16384 + (rt & 3) * 2048 + t * 8);
            *(short8*)&lds_a[t * 8] = x;
        }
        {
            float4 g4 = *(const float4*)(gvb + (size_t)(crow + r_s) * 128 + dd0);
            uint2 p = make_uint2(pkhu(s4.x * g4.x, s4.y * g4.y),
                                 pkhu(s4.z * g4.z, s4.w * g4.w));
            *(uint2*)&lds_a[lw] = p;
        }
        {
            float4 v4 = *(const float4*)(v + ((size_t)kb2 * 128 + crow + r_s) * 128 + dd0);
            uint2 p = make_uint2(pkhu(gs4.x * v4.x, gs4.y * v4.y),
                                 pkhu(gs4.z * v4.z, gs4.w * v4.w));
            *(uint2*)&lds_a[lw + 2048] = p;
        }
        __syncthreads();
        // ---- compute ----
        f32x4 acc = {0.f, 0.f, 0.f, 0.f};
        #pragma unroll
        for (int kk = 0; kk < 12; ++kk) {
            short8 a = *(const short8*)&lds_a[kk * 512 + kgrp * 128 + ln15 * 8];
            acc = __builtin_amdgcn_mfma_f32_16x16x32_bf16(
                a, __builtin_bit_cast(short8, wreg[kk]), acc, 0, 0, 0);
        }
        int e = ct * 16 + ln15;
        #pragma unroll
        for (int q = 0; q < 4; ++q) {
            int row = crow + kgrp * 4 + q;
            outp[(size_t)row * 128 + e] = acc[q];
            psum = fmaf(gvb[(size_t)row * 128 + e], acc[q], psum);
        }
        __syncthreads();
    }
    psum += __shfl_xor(psum, 16);
    psum += __shfl_xor(psum, 32);
    if (kgrp == 0) svv[(size_t)kb2 * 128 + ct * 16 + ln15] = psum;
}

// ---------------- K4: s-path linears + products + MLP -------------------------
__global__ __launch_bounds__(256) void k4_spath(
        const float* __restrict__ s, const float* __restrict__ svv,
        const float* __restrict__ g1,
        const float* __restrict__ wT2, const float* __restrict__ lin2_b,
        const float* __restrict__ wT3, const float* __restrict__ lin3_b,
        const float* __restrict__ wTm1, const float* __restrict__ mlp_b1,
        const float* __restrict__ wTm2, const float* __restrict__ mlp_b2,
        float* __restrict__ sout) {
    __shared__ float xs[8][128], xv[8][128], pre[8][128], hbuf[8][128];
    int t = threadIdx.x;
    int rowb = blockIdx.x * 8;
    int b = rowb >> 8;
    #pragma unroll
    for (int i = 0; i < 4; ++i) {
        int vi = i * 256 + t;
        int r = vi >> 7, dd = vi & 127;
        xs[r][dd] = s[(size_t)(rowb + r) * 128 + dd];
        xv[r][dd] = svv[(size_t)(rowb + r) * 128 + dd];
    }
    __syncthreads();
    int e = t & 127, h2 = t >> 7;
    float b2 = lin2_b[e], b3 = lin3_b[e], g1v = g1[b * 128 + e];
    float a2[4] = {b2, b2, b2, b2}, a3[4] = {b3, b3, b3, b3};
    for (int dd = 0; dd < 128; ++dd) {
        float w2 = wT2[dd * 128 + e], w3 = wT3[dd * 128 + e];
        #pragma unroll
        for (int r = 0; r < 4; ++r) {
            a2[r] = fmaf(xs[h2 * 4 + r][dd], w2, a2[r]);
            a3[r] = fmaf(xv[h2 * 4 + r][dd], w3, a3[r]);
        }
    }
    #pragma unroll
    for (int r = 0; r < 4; ++r) pre[h2 * 4 + r][e] = g1v * a2[r] * a3[r];
    __syncthreads();
    float bm1 = mlp_b1[e];
    float ah[4] = {bm1, bm1, bm1, bm1};
    for (int dd = 0; dd < 128; ++dd) {
        float w = wTm1[dd * 128 + e];
        #pragma unroll
        for (int r = 0; r < 4; ++r) ah[r] = fmaf(pre[h2 * 4 + r][dd], w, ah[r]);
    }
    #pragma unroll
    for (int r = 0; r < 4; ++r) hbuf[h2 * 4 + r][e] = fmaxf(ah[r], 0.f);
    __syncthreads();
    float bm2 = mlp_b2[e];
    float ao[4] = {bm2, bm2, bm2, bm2};
    for (int dd = 0; dd < 128; ++dd) {
        float w = wTm2[dd * 128 + e];
        #pragma unroll
        for (int r = 0; r < 4; ++r) ao[r] = fmaf(hbuf[h2 * 4 + r][dd], w, ao[r]);
    }
    #pragma unroll
    for (int r = 0; r < 4; ++r) sout[(size_t)(rowb + h2 * 4 + r) * 128 + e] = ao[r];
}

extern "C" void kernel_launch(void* const* d_in, const int* in_sizes, int n_in,
                              void* d_out, int out_size, void* d_ws, size_t ws_size,
                              hipStream_t stream) {
    const float* s       = (const float*)d_in[0];
    const float* v       = (const float*)d_in[1];
    const float* gs      = (const float*)d_in[2];
    const float* gv      = (const float*)d_in[3];
    const float* gv2     = (const float*)d_in[4];
    const float* lin1_w  = (const float*)d_in[5];
    const float* lin1_b  = (const float*)d_in[6];
    const float* lin2_w  = (const float*)d_in[7];
    const float* lin2_b  = (const float*)d_in[8];
    const float* lin3_w  = (const float*)d_in[9];
    const float* lin3_b  = (const float*)d_in[10];
    const float* linv1_w = (const float*)d_in[11];
    const float* linv2_w = (const float*)d_in[12];
    const float* linv3_w = (const float*)d_in[13];
    const float* mlp_w1  = (const float*)d_in[14];
    const float* mlp_b1  = (const float*)d_in[15];
    const float* mlp_w2  = (const float*)d_in[16];
    const float* mlp_b2  = (const float*)d_in[17];

    float* sout = (float*)d_out;
    float* vnew = (float*)d_out + 262144;   // v_new region; doubles as T2 (bf16)

    float* wsf   = (float*)d_ws;
    float* wT2   = wsf;
    float* wT3   = wsf + 16384;
    float* wTm1  = wsf + 32768;
    float* wTm2  = wsf + 49152;
    float* s_v2t = wsf + 65536;
    float* g1    = wsf + 66560;
    float* svv   = wsf + 67584;
    unsigned short* wfrag = (unsigned short*)(wsf + 329728);           // 96 KB
    unsigned short* vT  = (unsigned short*)((char*)d_ws + 2097152);    // 67.1 MB
    unsigned short* gT  = (unsigned short*)((char*)d_ws + 69206016);   // 33.5 MB
    bool big = ws_size >= 102760448ULL;

    k0a_prep<<<448, 256, 0, stream>>>(lin2_w, lin3_w, mlp_w1, mlp_w2,
                                      linv1_w, linv2_w, linv3_w,
                                      wT2, wT3, wTm1, wTm2, wfrag);
    k0b_trace<<<8, 128, 0, stream>>>(gv2, s_v2t);
    k0c_g1<<<8, 128, 0, stream>>>(s_v2t, lin1_w, lin1_b, gs, g1);
    if (big) {
        kt_v<<<2048, 256, 0, stream>>>(v, vT);
        kt_g<<<1024, 256, 0, stream>>>(gv2, gT);
        k1_T2_fast<<<1024, 512, 0, stream>>>(vT, gT, (unsigned short*)vnew);
    } else {
        k1_T2_legacy<<<1024, 512, 0, stream>>>(v, gv2, (unsigned short*)vnew);
    }
    k2_vnew_w<<<2048, 512, 0, stream>>>(s, v, gs, gv, wfrag, vnew, svv);
    k4_spath<<<256, 256, 0, stream>>>(s, svv, g1, wT2, lin2_b, wT3, lin3_b,
                                      wTm1, mlp_b1, wTm2, mlp_b2, sout);
}

// Round 11
// 252.786 us; speedup vs baseline: 1.0949x; 1.0243x over previous
//
#include <hip/hip_runtime.h>
#include <hip/hip_bf16.h>
#include <stdint.h>

#define B_ 8
#define N_ 256
#define M_ 128
#define D_ 128

typedef __attribute__((ext_vector_type(8))) short short8;
typedef __attribute__((ext_vector_type(4))) short short4v;
typedef __attribute__((ext_vector_type(4))) float f32x4;

static __device__ __forceinline__ unsigned short f2bf(float x) {
    union { float f; unsigned int u; } c; c.f = x;
    unsigned int r = (c.u + 0x7FFFu + ((c.u >> 16) & 1u)) >> 16;
    return (unsigned short)r;
}
static __device__ __forceinline__ unsigned short bfhu(float x) {
    union { float f; unsigned int u; } c; c.f = x;
    return (unsigned short)((c.u + 0x8000u) >> 16);
}
static __device__ __forceinline__ unsigned int pkhu(float a, float b) {
    union { float f; unsigned int u; } ca, cb; ca.f = a; cb.f = b;
    return ((ca.u + 0x8000u) >> 16) | ((cb.u + 0x8000u) & 0xFFFF0000u);
}

// ---------------- K0a: weight transposes (fp32) + wfrag (bf16, frag order) ---
__global__ void k0a_prep(const float* __restrict__ lin2_w, const float* __restrict__ lin3_w,
                         const float* __restrict__ mlp_w1, const float* __restrict__ mlp_w2,
                         const float* __restrict__ linv1_w, const float* __restrict__ linv2_w,
                         const float* __restrict__ linv3_w,
                         float* __restrict__ wT2, float* __restrict__ wT3,
                         float* __restrict__ wTm1, float* __restrict__ wTm2,
                         unsigned short* __restrict__ wfrag) {
    int gid = blockIdx.x * 256 + threadIdx.x;
    int task = gid >> 14;
    int idx = gid & 16383;
    if (task < 4) {
        int e = idx & 127, dd = idx >> 7;
        const float* src = task == 0 ? lin2_w : task == 1 ? lin3_w : task == 2 ? mlp_w1 : mlp_w2;
        float* dst = task == 0 ? wT2 : task == 1 ? wT3 : task == 2 ? wTm1 : wTm2;
        dst[dd * 128 + e] = src[e * 128 + dd];
    } else {
        int mat = task - 4;
        const float* src = mat == 0 ? linv1_w : mat == 1 ? linv2_w : linv3_w;
        int e = idx >> 7, k = idx & 127;
        int dst = ((((e >> 4) * 12 + (mat * 4 + (k >> 5))) * 4 + ((k >> 3) & 3)) * 16 + (e & 15)) * 8
                  + (k & 7);
        wfrag[dst] = f2bf(src[idx] * (1.0f / 3.0f));
    }
}

// ---------------- K0b: s_v2t[b,d] = sum_m gv2[b,m,m,d] ------------------------
__global__ void k0b_trace(const float* __restrict__ gv2, float* __restrict__ s_v2t) {
    int b = blockIdx.x, d = threadIdx.x;
    const float* p = gv2 + (size_t)b * (M_ * M_ * D_) + d;
    float acc = 0.f;
    #pragma unroll 8
    for (int m = 0; m < 128; ++m) acc += p[(size_t)m * 16512];
    s_v2t[b * 128 + d] = acc;
}

// ---------------- K0c: g1[b,e] = (lin1(s_v2t)+b1)*gs --------------------------
__global__ void k0c_g1(const float* __restrict__ s_v2t, const float* __restrict__ lin1_w,
                       const float* __restrict__ lin1_b, const float* __restrict__ gs,
                       float* __restrict__ g1) {
    __shared__ float sv[128];
    int b = blockIdx.x, e = threadIdx.x;
    sv[e] = s_v2t[b * 128 + e];
    __syncthreads();
    const float* w = lin1_w + e * 128;
    float acc = 0.f;
    #pragma unroll 4
    for (int dd = 0; dd < 128; ++dd) acc = fmaf(sv[dd], w[dd], acc);
    g1[b * 128 + e] = (acc + lin1_b[e]) * gs[b * 128 + e];
}

// ---------------- KT_v: vT[b,d,n*M+m] = bf16(v[b,n,m,d]) (R8-verified) --------
__global__ __launch_bounds__(256) void kt_v(const float* __restrict__ v,
                                            unsigned short* __restrict__ vT) {
    __shared__ unsigned short tl[128 * 136];
    int bid = blockIdx.x;
    int b = bid >> 8;
    int R0 = (bid & 255) * 128;
    int t = threadIdx.x;
    const float* src = v + ((size_t)b * 32768 + R0) * 128;
    #pragma unroll
    for (int i = 0; i < 16; ++i) {
        int flat = i * 256 + t;
        int row = flat >> 5, slot = flat & 31;
        float4 x = *(const float4*)(src + (size_t)row * 128 + slot * 4);
        #pragma unroll
        for (int j = 0; j < 4; ++j) {
            int d = slot * 4 + j;
            tl[d * 136 + (row ^ (((d >> 2) & 7) << 3))] = bfhu(((const float*)&x)[j]);
        }
    }
    __syncthreads();
    #pragma unroll
    for (int i = 0; i < 8; ++i) {
        int flat = i * 256 + t;
        int d = flat >> 4, rs = flat & 15;
        short8 y = *(const short8*)&tl[d * 136 + ((rs * 8) ^ (((d >> 2) & 7) << 3))];
        *(short8*)(vT + (size_t)(b * 128 + d) * 32768 + R0 + rs * 8) = y;
    }
}

// ---------------- KT_g: gT[b,d,c,m] = bf16(gv2[b,m,c,d]) ----------------------
__global__ __launch_bounds__(256) void kt_g(const float* __restrict__ gv2,
                                            unsigned short* __restrict__ gT) {
    __shared__ unsigned short tl[128 * 136];
    int bid = blockIdx.x;
    int b = bid >> 7;
    int c = bid & 127;
    int t = threadIdx.x;
    const float* src = gv2 + ((size_t)(b * 128) * 128 + c) * 128;
    #pragma unroll
    for (int i = 0; i < 16; ++i) {
        int flat = i * 256 + t;
        int m = flat >> 5, slot = flat & 31;
        float4 x = *(const float4*)(src + (size_t)m * 16384 + slot * 4);
        #pragma unroll
        for (int j = 0; j < 4; ++j) {
            int d = slot * 4 + j;
            tl[d * 136 + (m ^ (((d >> 2) & 7) << 3))] = bfhu(((const float*)&x)[j]);
        }
    }
    __syncthreads();
    #pragma unroll
    for (int i = 0; i < 8; ++i) {
        int flat = i * 256 + t;
        int d = flat >> 4, ms = flat & 15;
        short8 y = *(const short8*)&tl[d * 136 + ((ms * 8) ^ (((d >> 2) & 7) << 3))];
        *(short8*)(gT + ((size_t)(b * 128 + d) * 128 + c) * 128 + ms * 8) = y;
    }
}

// ---------------- K1fast: T2 GEMM from pre-transposed bf16 inputs -------------
__global__ __launch_bounds__(512, 2) void k1_T2_fast(const unsigned short* __restrict__ vT,
                                                     const unsigned short* __restrict__ gT,
                                                     unsigned short* __restrict__ t2base) {
    __shared__ unsigned short sm[40960];
    int bid = blockIdx.x;
    int b = bid & 7;
    int r = bid >> 3;
    int nt = r & 3, ch = (r >> 2) & 1, dc = r >> 3;
    int n0 = nt * 64, c0 = ch * 64, d0 = dc * 8;
    int t = threadIdx.x;
    int w = t >> 6, lane = t & 63, ln15 = lane & 15, kg = lane >> 4;

    f32x4 acc[4][4];
    #pragma unroll
    for (int i = 0; i < 4; ++i)
        #pragma unroll
        for (int j = 0; j < 4; ++j) acc[i][j] = (f32x4){0.f, 0.f, 0.f, 0.f};

    for (int mc = 0; mc < 4; ++mc) {
        int m0 = mc * 32;
        #pragma unroll
        for (int i = 0; i < 4; ++i) {
            int flat = i * 512 + t;
            int d = flat >> 8, x = (flat >> 2) & 63, ms = flat & 3;
            short8 a = *(const short8*)(vT + ((size_t)(b * 128 + d0 + d) * 256 + n0 + x) * 128
                                           + m0 + ms * 8);
            *(short8*)&sm[d * 2560 + x * 40 + ms * 8] = a;
            short8 g = *(const short8*)(gT + ((size_t)(b * 128 + d0 + d) * 128 + c0 + x) * 128
                                           + m0 + ms * 8);
            *(short8*)&sm[20480 + d * 2560 + x * 40 + ms * 8] = g;
        }
        __syncthreads();
        short8 af[4], bf[4];
        #pragma unroll
        for (int i = 0; i < 4; ++i)
            af[i] = *(const short8*)&sm[w * 2560 + (i * 16 + ln15) * 40 + kg * 8];
        #pragma unroll
        for (int j = 0; j < 4; ++j)
            bf[j] = *(const short8*)&sm[20480 + w * 2560 + (j * 16 + ln15) * 40 + kg * 8];
        #pragma unroll
        for (int i = 0; i < 4; ++i)
            #pragma unroll
            for (int j = 0; j < 4; ++j)
                acc[i][j] = __builtin_amdgcn_mfma_f32_16x16x32_bf16(af[i], bf[j], acc[i][j], 0, 0, 0);
        __syncthreads();
    }
    #pragma unroll
    for (int i = 0; i < 4; ++i)
        #pragma unroll
        for (int j = 0; j < 4; ++j)
            #pragma unroll
            for (int q = 0; q < 4; ++q) {
                int n = i * 16 + kg * 4 + q;
                int c = j * 16 + ln15;
                sm[n * 520 + c * 8 + w] = bfhu(acc[i][j][q]);
            }
    __syncthreads();
    #pragma unroll
    for (int p = 0; p < 8; ++p) {
        int u = p * 512 + t;
        int n = u >> 6;
        int c = u & 63;
        short8 x = *(const short8*)&sm[n * 520 + c * 8];
        size_t kb = (size_t)(b * N_ + n0 + n) * 2 + ch;
        *(short8*)(t2base + kb * 16384 + (size_t)((c >> 4) * 16 + dc) * 128 + (c & 15) * 8) = x;
    }
}

// ---------------- K1 legacy (fallback) ----------------------------------------
__global__ __launch_bounds__(512, 4) void k1_T2_legacy(const float* __restrict__ v,
                                                       const float* __restrict__ gv2,
                                                       unsigned short* __restrict__ t2base) {
    __shared__ unsigned short sm[40960];
    int bid = blockIdx.x;
    int b = bid & 7;
    int r = bid >> 3;
    int nt = r & 3, ch = (r >> 2) & 1, dc = r >> 3;
    int n0 = nt * 64, c0 = ch * 64, d0 = dc * 8;
    int t = threadIdx.x;
    int w = t >> 6, lane = t & 63, ln15 = lane & 15, kg = lane >> 4;

    f32x4 acc[4][4];
    #pragma unroll
    for (int i = 0; i < 4; ++i)
        #pragma unroll
        for (int j = 0; j < 4; ++j) acc[i][j] = (f32x4){0.f, 0.f, 0.f, 0.f};

    int d0l = (t & 1) * 4;
    int am = (t >> 1) & 31, anb = t >> 6;
    int bc = (t >> 1) & 63, bmb = t >> 7;

    for (int mc = 0; mc < 4; ++mc) {
        int m0 = mc * 32;
        {
            const float* src = v + (((size_t)(b * N_ + n0) * M_ + m0 + am) * D_ + d0 + d0l);
            #pragma unroll
            for (int p = 0; p < 8; ++p) {
                int n = p * 8 + anb;
                float4 x = *(const float4*)(src + (size_t)n * (M_ * D_));
                #pragma unroll
                for (int j = 0; j < 4; ++j)
                    sm[(d0l + j) * 2560 + n * 40 + am] = f2bf(((const float*)&x)[j]);
            }
        }
        {
            const float* src = gv2 + (((size_t)(b * M_ + m0) * M_ + c0 + bc) * D_ + d0 + d0l);
            #pragma unroll
            for (int p = 0; p < 8; ++p) {
                int m = p * 4 + bmb;
                float4 x = *(const float4*)(src + (size_t)m * (M_ * D_));
                #pragma unroll
                for (int j = 0; j < 4; ++j)
                    sm[20480 + (d0l + j) * 2560 + bc * 40 + m] = f2bf(((const float*)&x)[j]);
            }
        }
        __syncthreads();
        short8 af[4], bf[4];
        #pragma unroll
        for (int i = 0; i < 4; ++i)
            af[i] = *(const short8*)&sm[w * 2560 + (i * 16 + ln15) * 40 + kg * 8];
        #pragma unroll
        for (int j = 0; j < 4; ++j)
            bf[j] = *(const short8*)&sm[20480 + w * 2560 + (j * 16 + ln15) * 40 + kg * 8];
        #pragma unroll
        for (int i = 0; i < 4; ++i)
            #pragma unroll
            for (int j = 0; j < 4; ++j)
                acc[i][j] = __builtin_amdgcn_mfma_f32_16x16x32_bf16(af[i], bf[j], acc[i][j], 0, 0, 0);
        __syncthreads();
    }
    #pragma unroll
    for (int i = 0; i < 4; ++i)
        #pragma unroll
        for (int j = 0; j < 4; ++j)
            #pragma unroll
            for (int q = 0; q < 4; ++q) {
                int n = i * 16 + kg * 4 + q;
                int c = j * 16 + ln15;
                sm[(n * 64 + c) * 8 + w] = f2bf(acc[i][j][q]);
            }
    __syncthreads();
    #pragma unroll
    for (int p = 0; p < 8; ++p) {
        int u = p * 512 + t;
        int n = u >> 6;
        int c = u & 63;
        short8 x = *(const short8*)&sm[(n * 64 + c) * 8];
        size_t kb = (size_t)(b * N_ + n0 + n) * 2 + ch;
        *(short8*)(t2base + kb * 16384 + (size_t)((c >> 4) * 16 + dc) * 128 + (c & 15) * 8) = x;
    }
}

// ---------------- K2w2: weights in regs, A in 2x12KB LDS (dbuf + swizzle) -----
// Swizzle: u16 idx slot-bits [3:4] ^= kgrp-bits [7:8] on ALL writes and reads
// (derived statically: staging writes 8-way -> 2-way, reads stay clean).
// Double-buffer: STAGE_LOAD(rt_{j+1}) issued before compute(rt_j); ds_write
// after barrier (T14). Order {2,3,1,0,6,7,5,4}: chunk(rt_{j+1}) disjoint from
// out(rt_i) for all i<=j  -> in-place T2 prefetch is race-free.
__global__ __launch_bounds__(512, 4) void k2_vnew_w(
        const float* __restrict__ s, const float* __restrict__ v,
        const float* __restrict__ gs, const float* __restrict__ gv,
        const unsigned short* __restrict__ wfrag,
        float* __restrict__ vnew, float* __restrict__ svv) {
    __shared__ unsigned short lds_a[2][6144];
    int t = threadIdx.x;
    int kb2 = blockIdx.x;              // b*256 + n
    int b = kb2 >> 8;
    int w = t >> 6, lane = t & 63, ln15 = lane & 15, kgrp = lane >> 4;
    int ct = w;

    f32x4 wreg[12];
    #pragma unroll
    for (int kk = 0; kk < 12; ++kk)
        wreg[kk] = *(const f32x4*)&wfrag[(((ct * 12 + kk) * 4 + kgrp) * 16 + ln15) * 8];
    asm volatile("" : "+v"(wreg[0]), "+v"(wreg[1]), "+v"(wreg[2]), "+v"(wreg[3]),
                      "+v"(wreg[4]), "+v"(wreg[5]), "+v"(wreg[6]), "+v"(wreg[7]),
                      "+v"(wreg[8]), "+v"(wreg[9]), "+v"(wreg[10]), "+v"(wreg[11]));

    int r_s = t >> 5;                  // staging row 0..15
    int q5 = t & 31;                   // dd-quad 0..31
    int dd0 = q5 * 4;
    int kgq = (q5 >> 1) & 3;           // kgrp of this quad
    // pre-swizzled derived-write index (within one 2048-u16 segment)
    int lw = (q5 >> 3) * 512 + kgq * 128 + ((r_s ^ kgq) * 8) + (q5 & 1) * 4;
    // pre-swizzled T2-stage index (t<256): t*8 with slot ^= kgrp
    int st2 = (t * 8) ^ (((t >> 4) & 3) << 3);

    float4 s4  = *(const float4*)(s + (size_t)kb2 * 128 + dd0);
    float4 gs4 = *(const float4*)(gs + (size_t)b * 128 + dd0);
    const float* gvb = gv + (size_t)b * 16384;
    const unsigned short* t2u = (const unsigned short*)(vnew + (size_t)kb2 * 16384);
    float* outp = vnew + (size_t)kb2 * 16384;

    short8 t2r;
    float4 g4, v4;
    float psum = 0.f;

    // prologue: load + write buffer 0 for rt=2
    {
        int rt = 2;
        int crow = (rt >> 2) * 64 + (rt & 3) * 16;
        if (t < 256) t2r = *(const short8*)(t2u + (rt >> 2) * 16384 + (rt & 3) * 2048 + t * 8);
        g4 = *(const float4*)(gvb + (size_t)(crow + r_s) * 128 + dd0);
        v4 = *(const float4*)(v + ((size_t)kb2 * 128 + crow + r_s) * 128 + dd0);
        if (t < 256) *(short8*)&lds_a[0][st2] = t2r;
        uint2 p1 = make_uint2(pkhu(s4.x * g4.x, s4.y * g4.y), pkhu(s4.z * g4.z, s4.w * g4.w));
        *(uint2*)&lds_a[0][2048 + lw] = p1;
        uint2 p2 = make_uint2(pkhu(gs4.x * v4.x, gs4.y * v4.y), pkhu(gs4.z * v4.z, gs4.w * v4.w));
        *(uint2*)&lds_a[0][4096 + lw] = p2;
    }
    __syncthreads();

    #pragma unroll
    for (int j = 0; j < 8; ++j) {
        int rt = (0x45760132u >> (4 * j)) & 7;       // {2,3,1,0,6,7,5,4}
        int cur = j & 1;
        // prefetch next iteration's globals (safe: chunk(next) disjoint from
        // all outputs written so far, incl. this iteration's)
        if (j < 7) {
            int rtn = (0x45760132u >> (4 * (j + 1))) & 7;
            int crn = (rtn >> 2) * 64 + (rtn & 3) * 16;
            if (t < 256) t2r = *(const short8*)(t2u + (rtn >> 2) * 16384 + (rtn & 3) * 2048 + t * 8);
            g4 = *(const float4*)(gvb + (size_t)(crn + r_s) * 128 + dd0);
            v4 = *(const float4*)(v + ((size_t)kb2 * 128 + crn + r_s) * 128 + dd0);
        }
        // compute from buf[cur]
        f32x4 acc = {0.f, 0.f, 0.f, 0.f};
        #pragma unroll
        for (int kk = 0; kk < 12; ++kk) {
            short8 a = *(const short8*)&lds_a[cur][kk * 512 + kgrp * 128 + ((ln15 ^ kgrp) * 8)];
            acc = __builtin_amdgcn_mfma_f32_16x16x32_bf16(
                a, __builtin_bit_cast(short8, wreg[kk]), acc, 0, 0, 0);
        }
        int crow = (rt >> 2) * 64 + (rt & 3) * 16;
        int e = ct * 16 + ln15;
        #pragma unroll
        for (int q = 0; q < 4; ++q) {
            int row = crow + kgrp * 4 + q;
            outp[(size_t)row * 128 + e] = acc[q];
            psum = fmaf(gvb[(size_t)row * 128 + e], acc[q], psum);
        }
        if (j < 7) {
            __syncthreads();           // everyone done reading buf[cur^1] (2 barriers ago)
            if (t < 256) *(short8*)&lds_a[cur ^ 1][st2] = t2r;
            uint2 p1 = make_uint2(pkhu(s4.x * g4.x, s4.y * g4.y), pkhu(s4.z * g4.z, s4.w * g4.w));
            *(uint2*)&lds_a[cur ^ 1][2048 + lw] = p1;
            uint2 p2 = make_uint2(pkhu(gs4.x * v4.x, gs4.y * v4.y),
                                  pkhu(gs4.z * v4.z, gs4.w * v4.w));
            *(uint2*)&lds_a[cur ^ 1][4096 + lw] = p2;
            __syncthreads();
        }
    }
    psum += __shfl_xor(psum, 16);
    psum += __shfl_xor(psum, 32);
    if (kgrp == 0) svv[(size_t)kb2 * 128 + ct * 16 + ln15] = psum;
}

// ---------------- K4: s-path linears + products + MLP -------------------------
__global__ __launch_bounds__(256) void k4_spath(
        const float* __restrict__ s, const float* __restrict__ svv,
        const float* __restrict__ g1,
        const float* __restrict__ wT2, const float* __restrict__ lin2_b,
        const float* __restrict__ wT3, const float* __restrict__ lin3_b,
        const float* __restrict__ wTm1, const float* __restrict__ mlp_b1,
        const float* __restrict__ wTm2, const float* __restrict__ mlp_b2,
        float* __restrict__ sout) {
    __shared__ float xs[8][128], xv[8][128], pre[8][128], hbuf[8][128];
    int t = threadIdx.x;
    int rowb = blockIdx.x * 8;
    int b = rowb >> 8;
    #pragma unroll
    for (int i = 0; i < 4; ++i) {
        int vi = i * 256 + t;
        int r = vi >> 7, dd = vi & 127;
        xs[r][dd] = s[(size_t)(rowb + r) * 128 + dd];
        xv[r][dd] = svv[(size_t)(rowb + r) * 128 + dd];
    }
    __syncthreads();
    int e = t & 127, h2 = t >> 7;
    float b2 = lin2_b[e], b3 = lin3_b[e], g1v = g1[b * 128 + e];
    float a2[4] = {b2, b2, b2, b2}, a3[4] = {b3, b3, b3, b3};
    for (int dd = 0; dd < 128; ++dd) {
        float w2 = wT2[dd * 128 + e], w3 = wT3[dd * 128 + e];
        #pragma unroll
        for (int r = 0; r < 4; ++r) {
            a2[r] = fmaf(xs[h2 * 4 + r][dd], w2, a2[r]);
            a3[r] = fmaf(xv[h2 * 4 + r][dd], w3, a3[r]);
        }
    }
    #pragma unroll
    for (int r = 0; r < 4; ++r) pre[h2 * 4 + r][e] = g1v * a2[r] * a3[r];
    __syncthreads();
    float bm1 = mlp_b1[e];
    float ah[4] = {bm1, bm1, bm1, bm1};
    for (int dd = 0; dd < 128; ++dd) {
        float w = wTm1[dd * 128 + e];
        #pragma unroll
        for (int r = 0; r < 4; ++r) ah[r] = fmaf(pre[h2 * 4 + r][dd], w, ah[r]);
    }
    #pragma unroll
    for (int r = 0; r < 4; ++r) hbuf[h2 * 4 + r][e] = fmaxf(ah[r], 0.f);
    __syncthreads();
    float bm2 = mlp_b2[e];
    float ao[4] = {bm2, bm2, bm2, bm2};
    for (int dd = 0; dd < 128; ++dd) {
        float w = wTm2[dd * 128 + e];
        #pragma unroll
        for (int r = 0; r < 4; ++r) ao[r] = fmaf(hbuf[h2 * 4 + r][dd], w, ao[r]);
    }
    #pragma unroll
    for (int r = 0; r < 4; ++r) sout[(size_t)(rowb + h2 * 4 + r) * 128 + e] = ao[r];
}

extern "C" void kernel_launch(void* const* d_in, const int* in_sizes, int n_in,
                              void* d_out, int out_size, void* d_ws, size_t ws_size,
                              hipStream_t stream) {
    const float* s       = (const float*)d_in[0];
    const float* v       = (const float*)d_in[1];
    const float* gs      = (const float*)d_in[2];
    const float* gv      = (const float*)d_in[3];
    const float* gv2     = (const float*)d_in[4];
    const float* lin1_w  = (const float*)d_in[5];
    const float* lin1_b  = (const float*)d_in[6];
    const float* lin2_w  = (const float*)d_in[7];
    const float* lin2_b  = (const float*)d_in[8];
    const float* lin3_w  = (const float*)d_in[9];
    const float* lin3_b  = (const float*)d_in[10];
    const float* linv1_w = (const float*)d_in[11];
    const float* linv2_w = (const float*)d_in[12];
    const float* linv3_w = (const float*)d_in[13];
    const float* mlp_w1  = (const float*)d_in[14];
    const float* mlp_b1  = (const float*)d_in[15];
    const float* mlp_w2  = (const float*)d_in[16];
    const float* mlp_b2  = (const float*)d_in[17];

    float* sout = (float*)d_out;
    float* vnew = (float*)d_out + 262144;   // v_new region; doubles as T2 (bf16)

    float* wsf   = (float*)d_ws;
    float* wT2   = wsf;
    float* wT3   = wsf + 16384;
    float* wTm1  = wsf + 32768;
    float* wTm2  = wsf + 49152;
    float* s_v2t = wsf + 65536;
    float* g1    = wsf + 66560;
    float* svv   = wsf + 67584;
    unsigned short* wfrag = (unsigned short*)(wsf + 329728);           // 96 KB
    unsigned short* vT  = (unsigned short*)((char*)d_ws + 2097152);    // 67.1 MB
    unsigned short* gT  = (unsigned short*)((char*)d_ws + 69206016);   // 33.5 MB
    bool big = ws_size >= 102760448ULL;

    k0a_prep<<<448, 256, 0, stream>>>(lin2_w, lin3_w, mlp_w1, mlp_w2,
                                      linv1_w, linv2_w, linv3_w,
                                      wT2, wT3, wTm1, wTm2, wfrag);
    k0b_trace<<<8, 128, 0, stream>>>(gv2, s_v2t);
    k0c_g1<<<8, 128, 0, stream>>>(s_v2t, lin1_w, lin1_b, gs, g1);
    if (big) {
        kt_v<<<2048, 256, 0, stream>>>(v, vT);
        kt_g<<<1024, 256, 0, stream>>>(gv2, gT);
        k1_T2_fast<<<1024, 512, 0, stream>>>(vT, gT, (unsigned short*)vnew);
    } else {
        k1_T2_legacy<<<1024, 512, 0, stream>>>(v, gv2, (unsigned short*)vnew);
    }
    k2_vnew_w<<<2048, 512, 0, stream>>>(s, v, gs, gv, wfrag, vnew, svv);
    k4_spath<<<256, 256, 0, stream>>>(s, svv, g1, wT2, lin2_b, wT3, lin3_b,
                                      wTm1, mlp_b1, wTm2, mlp_b2, sout);
}

// Round 12
// 249.334 us; speedup vs baseline: 1.1100x; 1.0138x over previous
//
#include <hip/hip_runtime.h>
#include <hip/hip_bf16.h>
#include <stdint.h>

#define B_ 8
#define N_ 256
#define M_ 128
#define D_ 128

typedef __attribute__((ext_vector_type(8))) short short8;
typedef __attribute__((ext_vector_type(4))) short short4v;
typedef __attribute__((ext_vector_type(4))) float f32x4;

static __device__ __forceinline__ unsigned short f2bf(float x) {
    union { float f; unsigned int u; } c; c.f = x;
    unsigned int r = (c.u + 0x7FFFu + ((c.u >> 16) & 1u)) >> 16;
    return (unsigned short)r;
}
static __device__ __forceinline__ unsigned short bfhu(float x) {
    union { float f; unsigned int u; } c; c.f = x;
    return (unsigned short)((c.u + 0x8000u) >> 16);
}
static __device__ __forceinline__ unsigned int pkhu(float a, float b) {
    union { float f; unsigned int u; } ca, cb; ca.f = a; cb.f = b;
    return ((ca.u + 0x8000u) >> 16) | ((cb.u + 0x8000u) & 0xFFFF0000u);
}

// ---------------- KT_ALL: kt_v + kt_g + k0a + k0b fused (by block range) ------
__global__ __launch_bounds__(256) void kt_all(
        const float* __restrict__ v, const float* __restrict__ gv2,
        const float* __restrict__ lin2_w, const float* __restrict__ lin3_w,
        const float* __restrict__ mlp_w1, const float* __restrict__ mlp_w2,
        const float* __restrict__ linv1_w, const float* __restrict__ linv2_w,
        const float* __restrict__ linv3_w,
        unsigned short* __restrict__ vT, unsigned short* __restrict__ gT,
        float* __restrict__ wT2, float* __restrict__ wT3,
        float* __restrict__ wTm1, float* __restrict__ wTm2,
        unsigned short* __restrict__ wfrag, float* __restrict__ s_v2t) {
    __shared__ unsigned short tl[128 * 136];
    int bid = blockIdx.x;
    int t = threadIdx.x;
    if (bid < 2048) {
        // kt_v: vT[b,d,n*M+m] = bf16(v[b,n,m,d])
        int b = bid >> 8;
        int R0 = (bid & 255) * 128;
        const float* src = v + ((size_t)b * 32768 + R0) * 128;
        #pragma unroll
        for (int i = 0; i < 16; ++i) {
            int flat = i * 256 + t;
            int row = flat >> 5, slot = flat & 31;
            float4 x = *(const float4*)(src + (size_t)row * 128 + slot * 4);
            #pragma unroll
            for (int j = 0; j < 4; ++j) {
                int d = slot * 4 + j;
                tl[d * 136 + (row ^ (((d >> 2) & 7) << 3))] = bfhu(((const float*)&x)[j]);
            }
        }
        __syncthreads();
        #pragma unroll
        for (int i = 0; i < 8; ++i) {
            int flat = i * 256 + t;
            int d = flat >> 4, rs = flat & 15;
            short8 y = *(const short8*)&tl[d * 136 + ((rs * 8) ^ (((d >> 2) & 7) << 3))];
            *(short8*)(vT + (size_t)(b * 128 + d) * 32768 + R0 + rs * 8) = y;
        }
    } else if (bid < 3072) {
        // kt_g: gT[b,d,c,m] = bf16(gv2[b,m,c,d])
        int lb = bid - 2048;
        int b = lb >> 7;
        int c = lb & 127;
        const float* src = gv2 + ((size_t)(b * 128) * 128 + c) * 128;
        #pragma unroll
        for (int i = 0; i < 16; ++i) {
            int flat = i * 256 + t;
            int m = flat >> 5, slot = flat & 31;
            float4 x = *(const float4*)(src + (size_t)m * 16384 + slot * 4);
            #pragma unroll
            for (int j = 0; j < 4; ++j) {
                int d = slot * 4 + j;
                tl[d * 136 + (m ^ (((d >> 2) & 7) << 3))] = bfhu(((const float*)&x)[j]);
            }
        }
        __syncthreads();
        #pragma unroll
        for (int i = 0; i < 8; ++i) {
            int flat = i * 256 + t;
            int d = flat >> 4, ms = flat & 15;
            short8 y = *(const short8*)&tl[d * 136 + ((ms * 8) ^ (((d >> 2) & 7) << 3))];
            *(short8*)(gT + ((size_t)(b * 128 + d) * 128 + c) * 128 + ms * 8) = y;
        }
    } else if (bid < 3520) {
        // k0a: weight transposes + wfrag
        int gid = (bid - 3072) * 256 + t;
        int task = gid >> 14;
        int idx = gid & 16383;
        if (task < 4) {
            int e = idx & 127, dd = idx >> 7;
            const float* src = task == 0 ? lin2_w : task == 1 ? lin3_w
                             : task == 2 ? mlp_w1 : mlp_w2;
            float* dst = task == 0 ? wT2 : task == 1 ? wT3 : task == 2 ? wTm1 : wTm2;
            dst[dd * 128 + e] = src[e * 128 + dd];
        } else {
            int mat = task - 4;
            const float* src = mat == 0 ? linv1_w : mat == 1 ? linv2_w : linv3_w;
            int e = idx >> 7, k = idx & 127;
            int dst = ((((e >> 4) * 12 + (mat * 4 + (k >> 5))) * 4 + ((k >> 3) & 3)) * 16
                       + (e & 15)) * 8 + (k & 7);
            wfrag[dst] = f2bf(src[idx] * (1.0f / 3.0f));
        }
    } else {
        // k0b: s_v2t[b,d] = sum_m gv2[b,m,m,d]
        if (t < 128) {
            int b = bid - 3520;
            const float* p = gv2 + (size_t)b * (M_ * M_ * D_) + t;
            float acc = 0.f;
            #pragma unroll 8
            for (int m = 0; m < 128; ++m) acc += p[(size_t)m * 16512];
            s_v2t[b * 128 + t] = acc;
        }
    }
}

// ---------------- K0c: g1[b,e] = (lin1(s_v2t)+b1)*gs --------------------------
__global__ void k0c_g1(const float* __restrict__ s_v2t, const float* __restrict__ lin1_w,
                       const float* __restrict__ lin1_b, const float* __restrict__ gs,
                       float* __restrict__ g1) {
    __shared__ float sv[128];
    int b = blockIdx.x, e = threadIdx.x;
    sv[e] = s_v2t[b * 128 + e];
    __syncthreads();
    const float* w = lin1_w + e * 128;
    float acc = 0.f;
    #pragma unroll 4
    for (int dd = 0; dd < 128; ++dd) acc = fmaf(sv[dd], w[dd], acc);
    g1[b * 128 + e] = (acc + lin1_b[e]) * gs[b * 128 + e];
}

// ---------------- K1fast: T2 GEMM from pre-transposed bf16 inputs (verified) --
__global__ __launch_bounds__(512, 2) void k1_T2_fast(const unsigned short* __restrict__ vT,
                                                     const unsigned short* __restrict__ gT,
                                                     unsigned short* __restrict__ t2base) {
    __shared__ unsigned short sm[40960];
    int bid = blockIdx.x;
    int b = bid & 7;
    int r = bid >> 3;
    int nt = r & 3, ch = (r >> 2) & 1, dc = r >> 3;
    int n0 = nt * 64, c0 = ch * 64, d0 = dc * 8;
    int t = threadIdx.x;
    int w = t >> 6, lane = t & 63, ln15 = lane & 15, kg = lane >> 4;

    f32x4 acc[4][4];
    #pragma unroll
    for (int i = 0; i < 4; ++i)
        #pragma unroll
        for (int j = 0; j < 4; ++j) acc[i][j] = (f32x4){0.f, 0.f, 0.f, 0.f};

    for (int mc = 0; mc < 4; ++mc) {
        int m0 = mc * 32;
        #pragma unroll
        for (int i = 0; i < 4; ++i) {
            int flat = i * 512 + t;
            int d = flat >> 8, x = (flat >> 2) & 63, ms = flat & 3;
            short8 a = *(const short8*)(vT + ((size_t)(b * 128 + d0 + d) * 256 + n0 + x) * 128
                                           + m0 + ms * 8);
            *(short8*)&sm[d * 2560 + x * 40 + ms * 8] = a;
            short8 g = *(const short8*)(gT + ((size_t)(b * 128 + d0 + d) * 128 + c0 + x) * 128
                                           + m0 + ms * 8);
            *(short8*)&sm[20480 + d * 2560 + x * 40 + ms * 8] = g;
        }
        __syncthreads();
        short8 af[4], bf[4];
        #pragma unroll
        for (int i = 0; i < 4; ++i)
            af[i] = *(const short8*)&sm[w * 2560 + (i * 16 + ln15) * 40 + kg * 8];
        #pragma unroll
        for (int j = 0; j < 4; ++j)
            bf[j] = *(const short8*)&sm[20480 + w * 2560 + (j * 16 + ln15) * 40 + kg * 8];
        #pragma unroll
        for (int i = 0; i < 4; ++i)
            #pragma unroll
            for (int j = 0; j < 4; ++j)
                acc[i][j] = __builtin_amdgcn_mfma_f32_16x16x32_bf16(af[i], bf[j], acc[i][j], 0, 0, 0);
        __syncthreads();
    }
    #pragma unroll
    for (int i = 0; i < 4; ++i)
        #pragma unroll
        for (int j = 0; j < 4; ++j)
            #pragma unroll
            for (int q = 0; q < 4; ++q) {
                int n = i * 16 + kg * 4 + q;
                int c = j * 16 + ln15;
                sm[n * 520 + c * 8 + w] = bfhu(acc[i][j][q]);
            }
    __syncthreads();
    #pragma unroll
    for (int p = 0; p < 8; ++p) {
        int u = p * 512 + t;
        int n = u >> 6;
        int c = u & 63;
        short8 x = *(const short8*)&sm[n * 520 + c * 8];
        size_t kb = (size_t)(b * N_ + n0 + n) * 2 + ch;
        *(short8*)(t2base + kb * 16384 + (size_t)((c >> 4) * 16 + dc) * 128 + (c & 15) * 8) = x;
    }
}

// ---------------- K1 legacy (fallback) ----------------------------------------
__global__ __launch_bounds__(512, 4) void k1_T2_legacy(const float* __restrict__ v,
                                                       const float* __restrict__ gv2,
                                                       unsigned short* __restrict__ t2base) {
    __shared__ unsigned short sm[40960];
    int bid = blockIdx.x;
    int b = bid & 7;
    int r = bid >> 3;
    int nt = r & 3, ch = (r >> 2) & 1, dc = r >> 3;
    int n0 = nt * 64, c0 = ch * 64, d0 = dc * 8;
    int t = threadIdx.x;
    int w = t >> 6, lane = t & 63, ln15 = lane & 15, kg = lane >> 4;

    f32x4 acc[4][4];
    #pragma unroll
    for (int i = 0; i < 4; ++i)
        #pragma unroll
        for (int j = 0; j < 4; ++j) acc[i][j] = (f32x4){0.f, 0.f, 0.f, 0.f};

    int d0l = (t & 1) * 4;
    int am = (t >> 1) & 31, anb = t >> 6;
    int bc = (t >> 1) & 63, bmb = t >> 7;

    for (int mc = 0; mc < 4; ++mc) {
        int m0 = mc * 32;
        {
            const float* src = v + (((size_t)(b * N_ + n0) * M_ + m0 + am) * D_ + d0 + d0l);
            #pragma unroll
            for (int p = 0; p < 8; ++p) {
                int n = p * 8 + anb;
                float4 x = *(const float4*)(src + (size_t)n * (M_ * D_));
                #pragma unroll
                for (int j = 0; j < 4; ++j)
                    sm[(d0l + j) * 2560 + n * 40 + am] = f2bf(((const float*)&x)[j]);
            }
        }
        {
            const float* src = gv2 + (((size_t)(b * M_ + m0) * M_ + c0 + bc) * D_ + d0 + d0l);
            #pragma unroll
            for (int p = 0; p < 8; ++p) {
                int m = p * 4 + bmb;
                float4 x = *(const float4*)(src + (size_t)m * (M_ * D_));
                #pragma unroll
                for (int j = 0; j < 4; ++j)
                    sm[20480 + (d0l + j) * 2560 + bc * 40 + m] = f2bf(((const float*)&x)[j]);
            }
        }
        __syncthreads();
        short8 af[4], bf[4];
        #pragma unroll
        for (int i = 0; i < 4; ++i)
            af[i] = *(const short8*)&sm[w * 2560 + (i * 16 + ln15) * 40 + kg * 8];
        #pragma unroll
        for (int j = 0; j < 4; ++j)
            bf[j] = *(const short8*)&sm[20480 + w * 2560 + (j * 16 + ln15) * 40 + kg * 8];
        #pragma unroll
        for (int i = 0; i < 4; ++i)
            #pragma unroll
            for (int j = 0; j < 4; ++j)
                acc[i][j] = __builtin_amdgcn_mfma_f32_16x16x32_bf16(af[i], bf[j], acc[i][j], 0, 0, 0);
        __syncthreads();
    }
    #pragma unroll
    for (int i = 0; i < 4; ++i)
        #pragma unroll
        for (int j = 0; j < 4; ++j)
            #pragma unroll
            for (int q = 0; q < 4; ++q) {
                int n = i * 16 + kg * 4 + q;
                int c = j * 16 + ln15;
                sm[(n * 64 + c) * 8 + w] = f2bf(acc[i][j][q]);
            }
    __syncthreads();
    #pragma unroll
    for (int p = 0; p < 8; ++p) {
        int u = p * 512 + t;
        int n = u >> 6;
        int c = u & 63;
        short8 x = *(const short8*)&sm[(n * 64 + c) * 8];
        size_t kb = (size_t)(b * N_ + n0 + n) * 2 + ch;
        *(short8*)(t2base + kb * 16384 + (size_t)((c >> 4) * 16 + dc) * 128 + (c & 15) * 8) = x;
    }
}

// ---------------- K2w3: half-split blocks, XCD-pinned, dbuf + swizzle ---------
// Two blocks per (b,n): half 0 handles rt {2,3,1,0} (rows 0-63), half 1
// {6,7,5,4} (rows 64-127). Chunk/output row ranges disjoint within and across
// halves (verified per-iteration). bid&7 == b -> same XCD as k1's T2 writer.
// s_vv partials: half0 -> svv, half1 -> svv2 (= sout region); k4 sums.
__global__ __launch_bounds__(512, 4) void k2_vnew_w(
        const float* __restrict__ s, const float* __restrict__ v,
        const float* __restrict__ gs, const float* __restrict__ gv,
        const unsigned short* __restrict__ wfrag,
        float* __restrict__ vnew, float* __restrict__ svv, float* __restrict__ svv2) {
    __shared__ unsigned short lds_a[2][6144];
    int t = threadIdx.x;
    int bid = blockIdx.x;
    int b = bid & 7;
    int rest = bid >> 3;
    int n = rest >> 1;
    int half = rest & 1;
    int kb2 = b * 256 + n;
    int pack = half ? 0x4576 : 0x0132;     // rt sequence, 4 nibbles
    int w = t >> 6, lane = t & 63, ln15 = lane & 15, kgrp = lane >> 4;
    int ct = w;

    f32x4 wreg[12];
    #pragma unroll
    for (int kk = 0; kk < 12; ++kk)
        wreg[kk] = *(const f32x4*)&wfrag[(((ct * 12 + kk) * 4 + kgrp) * 16 + ln15) * 8];
    asm volatile("" : "+v"(wreg[0]), "+v"(wreg[1]), "+v"(wreg[2]), "+v"(wreg[3]),
                      "+v"(wreg[4]), "+v"(wreg[5]), "+v"(wreg[6]), "+v"(wreg[7]),
                      "+v"(wreg[8]), "+v"(wreg[9]), "+v"(wreg[10]), "+v"(wreg[11]));

    int r_s = t >> 5;
    int q5 = t & 31;
    int dd0 = q5 * 4;
    int kgq = (q5 >> 1) & 3;
    int lw = (q5 >> 3) * 512 + kgq * 128 + ((r_s ^ kgq) * 8) + (q5 & 1) * 4;
    int st2 = (t * 8) ^ (((t >> 4) & 3) << 3);

    float4 s4  = *(const float4*)(s + (size_t)kb2 * 128 + dd0);
    float4 gs4 = *(const float4*)(gs + (size_t)b * 128 + dd0);
    const float* gvb = gv + (size_t)b * 16384;
    const unsigned short* t2u = (const unsigned short*)(vnew + (size_t)kb2 * 16384);
    float* outp = vnew + (size_t)kb2 * 16384;

    short8 t2r;
    float4 g4, v4;
    float psum = 0.f;

    {   // prologue: first rt of this half
        int rt = pack & 7;
        int crow = (rt >> 2) * 64 + (rt & 3) * 16;
        if (t < 256) t2r = *(const short8*)(t2u + (rt >> 2) * 16384 + (rt & 3) * 2048 + t * 8);
        g4 = *(const float4*)(gvb + (size_t)(crow + r_s) * 128 + dd0);
        v4 = *(const float4*)(v + ((size_t)kb2 * 128 + crow + r_s) * 128 + dd0);
        if (t < 256) *(short8*)&lds_a[0][st2] = t2r;
        uint2 p1 = make_uint2(pkhu(s4.x * g4.x, s4.y * g4.y), pkhu(s4.z * g4.z, s4.w * g4.w));
        *(uint2*)&lds_a[0][2048 + lw] = p1;
        uint2 p2 = make_uint2(pkhu(gs4.x * v4.x, gs4.y * v4.y), pkhu(gs4.z * v4.z, gs4.w * v4.w));
        *(uint2*)&lds_a[0][4096 + lw] = p2;
    }
    __syncthreads();

    #pragma unroll
    for (int j = 0; j < 4; ++j) {
        int rt = (pack >> (4 * j)) & 7;
        int cur = j & 1;
        if (j < 3) {
            int rtn = (pack >> (4 * (j + 1))) & 7;
            int crn = (rtn >> 2) * 64 + (rtn & 3) * 16;
            if (t < 256) t2r = *(const short8*)(t2u + (rtn >> 2) * 16384 + (rtn & 3) * 2048 + t * 8);
            g4 = *(const float4*)(gvb + (size_t)(crn + r_s) * 128 + dd0);
            v4 = *(const float4*)(v + ((size_t)kb2 * 128 + crn + r_s) * 128 + dd0);
        }
        f32x4 acc = {0.f, 0.f, 0.f, 0.f};
        #pragma unroll
        for (int kk = 0; kk < 12; ++kk) {
            short8 a = *(const short8*)&lds_a[cur][kk * 512 + kgrp * 128 + ((ln15 ^ kgrp) * 8)];
            acc = __builtin_amdgcn_mfma_f32_16x16x32_bf16(
                a, __builtin_bit_cast(short8, wreg[kk]), acc, 0, 0, 0);
        }
        int crow = (rt >> 2) * 64 + (rt & 3) * 16;
        int e = ct * 16 + ln15;
        #pragma unroll
        for (int q = 0; q < 4; ++q) {
            int row = crow + kgrp * 4 + q;
            outp[(size_t)row * 128 + e] = acc[q];
            psum = fmaf(gvb[(size_t)row * 128 + e], acc[q], psum);
        }
        if (j < 3) {
            __syncthreads();
            if (t < 256) *(short8*)&lds_a[cur ^ 1][st2] = t2r;
            uint2 p1 = make_uint2(pkhu(s4.x * g4.x, s4.y * g4.y), pkhu(s4.z * g4.z, s4.w * g4.w));
            *(uint2*)&lds_a[cur ^ 1][2048 + lw] = p1;
            uint2 p2 = make_uint2(pkhu(gs4.x * v4.x, gs4.y * v4.y),
                                  pkhu(gs4.z * v4.z, gs4.w * v4.w));
            *(uint2*)&lds_a[cur ^ 1][4096 + lw] = p2;
            __syncthreads();
        }
    }
    psum += __shfl_xor(psum, 16);
    psum += __shfl_xor(psum, 32);
    float* svvout = half ? svv2 : svv;
    if (kgrp == 0) svvout[(size_t)kb2 * 128 + ct * 16 + ln15] = psum;
}

// ---------------- K4: s-path linears + products + MLP (sums svv partials) -----
__global__ __launch_bounds__(256) void k4_spath(
        const float* __restrict__ s, const float* __restrict__ svv,
        const float* __restrict__ svv2, const float* __restrict__ g1,
        const float* __restrict__ wT2, const float* __restrict__ lin2_b,
        const float* __restrict__ wT3, const float* __restrict__ lin3_b,
        const float* __restrict__ wTm1, const float* __restrict__ mlp_b1,
        const float* __restrict__ wTm2, const float* __restrict__ mlp_b2,
        float* __restrict__ sout) {
    __shared__ float xs[8][128], xv[8][128], pre[8][128], hbuf[8][128];
    int t = threadIdx.x;
    int rowb = blockIdx.x * 8;
    int b = rowb >> 8;
    #pragma unroll
    for (int i = 0; i < 4; ++i) {
        int vi = i * 256 + t;
        int r = vi >> 7, dd = vi & 127;
        xs[r][dd] = s[(size_t)(rowb + r) * 128 + dd];
        xv[r][dd] = svv[(size_t)(rowb + r) * 128 + dd] + svv2[(size_t)(rowb + r) * 128 + dd];
    }
    __syncthreads();
    int e = t & 127, h2 = t >> 7;
    float b2 = lin2_b[e], b3 = lin3_b[e], g1v = g1[b * 128 + e];
    float a2[4] = {b2, b2, b2, b2}, a3[4] = {b3, b3, b3, b3};
    for (int dd = 0; dd < 128; ++dd) {
        float w2 = wT2[dd * 128 + e], w3 = wT3[dd * 128 + e];
        #pragma unroll
        for (int r = 0; r < 4; ++r) {
            a2[r] = fmaf(xs[h2 * 4 + r][dd], w2, a2[r]);
            a3[r] = fmaf(xv[h2 * 4 + r][dd], w3, a3[r]);
        }
    }
    #pragma unroll
    for (int r = 0; r < 4; ++r) pre[h2 * 4 + r][e] = g1v * a2[r] * a3[r];
    __syncthreads();
    float bm1 = mlp_b1[e];
    float ah[4] = {bm1, bm1, bm1, bm1};
    for (int dd = 0; dd < 128; ++dd) {
        float w = wTm1[dd * 128 + e];
        #pragma unroll
        for (int r = 0; r < 4; ++r) ah[r] = fmaf(pre[h2 * 4 + r][dd], w, ah[r]);
    }
    #pragma unroll
    for (int r = 0; r < 4; ++r) hbuf[h2 * 4 + r][e] = fmaxf(ah[r], 0.f);
    __syncthreads();
    float bm2 = mlp_b2[e];
    float ao[4] = {bm2, bm2, bm2, bm2};
    for (int dd = 0; dd < 128; ++dd) {
        float w = wTm2[dd * 128 + e];
        #pragma unroll
        for (int r = 0; r < 4; ++r) ao[r] = fmaf(hbuf[h2 * 4 + r][dd], w, ao[r]);
    }
    #pragma unroll
    for (int r = 0; r < 4; ++r) sout[(size_t)(rowb + h2 * 4 + r) * 128 + e] = ao[r];
}

extern "C" void kernel_launch(void* const* d_in, const int* in_sizes, int n_in,
                              void* d_out, int out_size, void* d_ws, size_t ws_size,
                              hipStream_t stream) {
    const float* s       = (const float*)d_in[0];
    const float* v       = (const float*)d_in[1];
    const float* gs      = (const float*)d_in[2];
    const float* gv      = (const float*)d_in[3];
    const float* gv2     = (const float*)d_in[4];
    const float* lin1_w  = (const float*)d_in[5];
    const float* lin1_b  = (const float*)d_in[6];
    const float* lin2_w  = (const float*)d_in[7];
    const float* lin2_b  = (const float*)d_in[8];
    const float* lin3_w  = (const float*)d_in[9];
    const float* lin3_b  = (const float*)d_in[10];
    const float* linv1_w = (const float*)d_in[11];
    const float* linv2_w = (const float*)d_in[12];
    const float* linv3_w = (const float*)d_in[13];
    const float* mlp_w1  = (const float*)d_in[14];
    const float* mlp_b1  = (const float*)d_in[15];
    const float* mlp_w2  = (const float*)d_in[16];
    const float* mlp_b2  = (const float*)d_in[17];

    float* sout = (float*)d_out;
    float* svv2 = (float*)d_out;            // k2-half1 partial; overwritten by k4
    float* vnew = (float*)d_out + 262144;   // v_new region; doubles as T2 (bf16)

    float* wsf   = (float*)d_ws;
    float* wT2   = wsf;
    float* wT3   = wsf + 16384;
    float* wTm1  = wsf + 32768;
    float* wTm2  = wsf + 49152;
    float* s_v2t = wsf + 65536;
    float* g1    = wsf + 66560;
    float* svv   = wsf + 67584;
    unsigned short* wfrag = (unsigned short*)(wsf + 329728);           // 96 KB
    unsigned short* vT  = (unsigned short*)((char*)d_ws + 2097152);    // 67.1 MB
    unsigned short* gT  = (unsigned short*)((char*)d_ws + 69206016);   // 33.5 MB
    bool big = ws_size >= 102760448ULL;

    if (big) {
        kt_all<<<3528, 256, 0, stream>>>(v, gv2, lin2_w, lin3_w, mlp_w1, mlp_w2,
                                         linv1_w, linv2_w, linv3_w, vT, gT,
                                         wT2, wT3, wTm1, wTm2, wfrag, s_v2t);
        k0c_g1<<<8, 128, 0, stream>>>(s_v2t, lin1_w, lin1_b, gs, g1);
        k1_T2_fast<<<1024, 512, 0, stream>>>(vT, gT, (unsigned short*)vnew);
    } else {
        kt_all<<<3528, 256, 0, stream>>>(v, gv2, lin2_w, lin3_w, mlp_w1, mlp_w2,
                                         linv1_w, linv2_w, linv3_w,
                                         (unsigned short*)(wsf + 200000),  // dummy small
                                         (unsigned short*)(wsf + 200000),
                                         wT2, wT3, wTm1, wTm2, wfrag, s_v2t);
        k0c_g1<<<8, 128, 0, stream>>>(s_v2t, lin1_w, lin1_b, gs, g1);
        k1_T2_legacy<<<1024, 512, 0, stream>>>(v, gv2, (unsigned short*)vnew);
    }
    k2_vnew_w<<<4096, 512, 0, stream>>>(s, v, gs, gv, wfrag, vnew, svv, svv2);
    k4_spath<<<256, 256, 0, stream>>>(s, svv, svv2, g1, wT2, lin2_b, wT3, lin3_b,
                                      wTm1, mlp_b1, wTm2, mlp_b2, sout);
}

// Round 13
// 236.293 us; speedup vs baseline: 1.1713x; 1.0552x over previous
//
#include <hip/hip_runtime.h>
#include <hip/hip_bf16.h>
#include <stdint.h>

#define B_ 8
#define N_ 256
#define M_ 128
#define D_ 128

typedef __attribute__((ext_vector_type(8))) short short8;
typedef __attribute__((ext_vector_type(4))) short short4v;
typedef __attribute__((ext_vector_type(4))) float f32x4;

static __device__ __forceinline__ unsigned short f2bf(float x) {
    union { float f; unsigned int u; } c; c.f = x;
    unsigned int r = (c.u + 0x7FFFu + ((c.u >> 16) & 1u)) >> 16;
    return (unsigned short)r;
}
static __device__ __forceinline__ unsigned short bfhu(float x) {
    union { float f; unsigned int u; } c; c.f = x;
    return (unsigned short)((c.u + 0x8000u) >> 16);
}
static __device__ __forceinline__ unsigned int pkhu(float a, float b) {
    union { float f; unsigned int u; } ca, cb; ca.f = a; cb.f = b;
    return ((ca.u + 0x8000u) >> 16) | ((cb.u + 0x8000u) & 0xFFFF0000u);
}

// ---------------- KT_ALL: kt_v + kt_g + k0a + k0b fused (by block range) ------
__global__ __launch_bounds__(256) void kt_all(
        const float* __restrict__ v, const float* __restrict__ gv2,
        const float* __restrict__ lin2_w, const float* __restrict__ lin3_w,
        const float* __restrict__ mlp_w1, const float* __restrict__ mlp_w2,
        const float* __restrict__ linv1_w, const float* __restrict__ linv2_w,
        const float* __restrict__ linv3_w,
        unsigned short* __restrict__ vT, unsigned short* __restrict__ gT,
        float* __restrict__ wT2, float* __restrict__ wT3,
        float* __restrict__ wTm1, float* __restrict__ wTm2,
        unsigned short* __restrict__ wfrag, float* __restrict__ s_v2t) {
    __shared__ unsigned short tl[128 * 136];
    int bid = blockIdx.x;
    int t = threadIdx.x;
    if (bid < 2048) {
        // kt_v: vT[b,d,n*M+m] = bf16(v[b,n,m,d])
        int b = bid >> 8;
        int R0 = (bid & 255) * 128;
        const float* src = v + ((size_t)b * 32768 + R0) * 128;
        #pragma unroll
        for (int i = 0; i < 16; ++i) {
            int flat = i * 256 + t;
            int row = flat >> 5, slot = flat & 31;
            float4 x = *(const float4*)(src + (size_t)row * 128 + slot * 4);
            #pragma unroll
            for (int j = 0; j < 4; ++j) {
                int d = slot * 4 + j;
                tl[d * 136 + (row ^ (((d >> 2) & 7) << 3))] = bfhu(((const float*)&x)[j]);
            }
        }
        __syncthreads();
        #pragma unroll
        for (int i = 0; i < 8; ++i) {
            int flat = i * 256 + t;
            int d = flat >> 4, rs = flat & 15;
            short8 y = *(const short8*)&tl[d * 136 + ((rs * 8) ^ (((d >> 2) & 7) << 3))];
            *(short8*)(vT + (size_t)(b * 128 + d) * 32768 + R0 + rs * 8) = y;
        }
    } else if (bid < 3072) {
        // kt_g: gT[b,d,c,m] = bf16(gv2[b,m,c,d])
        int lb = bid - 2048;
        int b = lb >> 7;
        int c = lb & 127;
        const float* src = gv2 + ((size_t)(b * 128) * 128 + c) * 128;
        #pragma unroll
        for (int i = 0; i < 16; ++i) {
            int flat = i * 256 + t;
            int m = flat >> 5, slot = flat & 31;
            float4 x = *(const float4*)(src + (size_t)m * 16384 + slot * 4);
            #pragma unroll
            for (int j = 0; j < 4; ++j) {
                int d = slot * 4 + j;
                tl[d * 136 + (m ^ (((d >> 2) & 7) << 3))] = bfhu(((const float*)&x)[j]);
            }
        }
        __syncthreads();
        #pragma unroll
        for (int i = 0; i < 8; ++i) {
            int flat = i * 256 + t;
            int d = flat >> 4, ms = flat & 15;
            short8 y = *(const short8*)&tl[d * 136 + ((ms * 8) ^ (((d >> 2) & 7) << 3))];
            *(short8*)(gT + ((size_t)(b * 128 + d) * 128 + c) * 128 + ms * 8) = y;
        }
    } else if (bid < 3520) {
        // k0a: weight transposes + wfrag
        int gid = (bid - 3072) * 256 + t;
        int task = gid >> 14;
        int idx = gid & 16383;
        if (task < 4) {
            int e = idx & 127, dd = idx >> 7;
            const float* src = task == 0 ? lin2_w : task == 1 ? lin3_w
                             : task == 2 ? mlp_w1 : mlp_w2;
            float* dst = task == 0 ? wT2 : task == 1 ? wT3 : task == 2 ? wTm1 : wTm2;
            dst[dd * 128 + e] = src[e * 128 + dd];
        } else {
            int mat = task - 4;
            const float* src = mat == 0 ? linv1_w : mat == 1 ? linv2_w : linv3_w;
            int e = idx >> 7, k = idx & 127;
            int dst = ((((e >> 4) * 12 + (mat * 4 + (k >> 5))) * 4 + ((k >> 3) & 3)) * 16
                       + (e & 15)) * 8 + (k & 7);
            wfrag[dst] = f2bf(src[idx] * (1.0f / 3.0f));
        }
    } else {
        // k0b: s_v2t[b,d] = sum_m gv2[b,m,m,d]
        if (t < 128) {
            int b = bid - 3520;
            const float* p = gv2 + (size_t)b * (M_ * M_ * D_) + t;
            float acc = 0.f;
            #pragma unroll 8
            for (int m = 0; m < 128; ++m) acc += p[(size_t)m * 16512];
            s_v2t[b * 128 + t] = acc;
        }
    }
}

// ---------------- K0c: g1[b,e] = (lin1(s_v2t)+b1)*gs --------------------------
__global__ void k0c_g1(const float* __restrict__ s_v2t, const float* __restrict__ lin1_w,
                       const float* __restrict__ lin1_b, const float* __restrict__ gs,
                       float* __restrict__ g1) {
    __shared__ float sv[128];
    int b = blockIdx.x, e = threadIdx.x;
    sv[e] = s_v2t[b * 128 + e];
    __syncthreads();
    const float* w = lin1_w + e * 128;
    float acc = 0.f;
    #pragma unroll 4
    for (int dd = 0; dd < 128; ++dd) acc = fmaf(sv[dd], w[dd], acc);
    g1[b * 128 + e] = (acc + lin1_b[e]) * gs[b * 128 + e];
}

// ---------------- K1fast: T2 GEMM from pre-transposed bf16 inputs (verified) --
__global__ __launch_bounds__(512, 2) void k1_T2_fast(const unsigned short* __restrict__ vT,
                                                     const unsigned short* __restrict__ gT,
                                                     unsigned short* __restrict__ t2base) {
    __shared__ unsigned short sm[40960];
    int bid = blockIdx.x;
    int b = bid & 7;
    int r = bid >> 3;
    int nt = r & 3, ch = (r >> 2) & 1, dc = r >> 3;
    int n0 = nt * 64, c0 = ch * 64, d0 = dc * 8;
    int t = threadIdx.x;
    int w = t >> 6, lane = t & 63, ln15 = lane & 15, kg = lane >> 4;

    f32x4 acc[4][4];
    #pragma unroll
    for (int i = 0; i < 4; ++i)
        #pragma unroll
        for (int j = 0; j < 4; ++j) acc[i][j] = (f32x4){0.f, 0.f, 0.f, 0.f};

    for (int mc = 0; mc < 4; ++mc) {
        int m0 = mc * 32;
        #pragma unroll
        for (int i = 0; i < 4; ++i) {
            int flat = i * 512 + t;
            int d = flat >> 8, x = (flat >> 2) & 63, ms = flat & 3;
            short8 a = *(const short8*)(vT + ((size_t)(b * 128 + d0 + d) * 256 + n0 + x) * 128
                                           + m0 + ms * 8);
            *(short8*)&sm[d * 2560 + x * 40 + ms * 8] = a;
            short8 g = *(const short8*)(gT + ((size_t)(b * 128 + d0 + d) * 128 + c0 + x) * 128
                                           + m0 + ms * 8);
            *(short8*)&sm[20480 + d * 2560 + x * 40 + ms * 8] = g;
        }
        __syncthreads();
        short8 af[4], bf[4];
        #pragma unroll
        for (int i = 0; i < 4; ++i)
            af[i] = *(const short8*)&sm[w * 2560 + (i * 16 + ln15) * 40 + kg * 8];
        #pragma unroll
        for (int j = 0; j < 4; ++j)
            bf[j] = *(const short8*)&sm[20480 + w * 2560 + (j * 16 + ln15) * 40 + kg * 8];
        #pragma unroll
        for (int i = 0; i < 4; ++i)
            #pragma unroll
            for (int j = 0; j < 4; ++j)
                acc[i][j] = __builtin_amdgcn_mfma_f32_16x16x32_bf16(af[i], bf[j], acc[i][j], 0, 0, 0);
        __syncthreads();
    }
    #pragma unroll
    for (int i = 0; i < 4; ++i)
        #pragma unroll
        for (int j = 0; j < 4; ++j)
            #pragma unroll
            for (int q = 0; q < 4; ++q) {
                int n = i * 16 + kg * 4 + q;
                int c = j * 16 + ln15;
                sm[n * 520 + c * 8 + w] = bfhu(acc[i][j][q]);
            }
    __syncthreads();
    #pragma unroll
    for (int p = 0; p < 8; ++p) {
        int u = p * 512 + t;
        int n = u >> 6;
        int c = u & 63;
        short8 x = *(const short8*)&sm[n * 520 + c * 8];
        size_t kb = (size_t)(b * N_ + n0 + n) * 2 + ch;
        *(short8*)(t2base + kb * 16384 + (size_t)((c >> 4) * 16 + dc) * 128 + (c & 15) * 8) = x;
    }
}

// ---------------- K1 legacy (fallback) ----------------------------------------
__global__ __launch_bounds__(512, 4) void k1_T2_legacy(const float* __restrict__ v,
                                                       const float* __restrict__ gv2,
                                                       unsigned short* __restrict__ t2base) {
    __shared__ unsigned short sm[40960];
    int bid = blockIdx.x;
    int b = bid & 7;
    int r = bid >> 3;
    int nt = r & 3, ch = (r >> 2) & 1, dc = r >> 3;
    int n0 = nt * 64, c0 = ch * 64, d0 = dc * 8;
    int t = threadIdx.x;
    int w = t >> 6, lane = t & 63, ln15 = lane & 15, kg = lane >> 4;

    f32x4 acc[4][4];
    #pragma unroll
    for (int i = 0; i < 4; ++i)
        #pragma unroll
        for (int j = 0; j < 4; ++j) acc[i][j] = (f32x4){0.f, 0.f, 0.f, 0.f};

    int d0l = (t & 1) * 4;
    int am = (t >> 1) & 31, anb = t >> 6;
    int bc = (t >> 1) & 63, bmb = t >> 7;

    for (int mc = 0; mc < 4; ++mc) {
        int m0 = mc * 32;
        {
            const float* src = v + (((size_t)(b * N_ + n0) * M_ + m0 + am) * D_ + d0 + d0l);
            #pragma unroll
            for (int p = 0; p < 8; ++p) {
                int n = p * 8 + anb;
                float4 x = *(const float4*)(src + (size_t)n * (M_ * D_));
                #pragma unroll
                for (int j = 0; j < 4; ++j)
                    sm[(d0l + j) * 2560 + n * 40 + am] = f2bf(((const float*)&x)[j]);
            }
        }
        {
            const float* src = gv2 + (((size_t)(b * M_ + m0) * M_ + c0 + bc) * D_ + d0 + d0l);
            #pragma unroll
            for (int p = 0; p < 8; ++p) {
                int m = p * 4 + bmb;
                float4 x = *(const float4*)(src + (size_t)m * (M_ * D_));
                #pragma unroll
                for (int j = 0; j < 4; ++j)
                    sm[20480 + (d0l + j) * 2560 + bc * 40 + m] = f2bf(((const float*)&x)[j]);
            }
        }
        __syncthreads();
        short8 af[4], bf[4];
        #pragma unroll
        for (int i = 0; i < 4; ++i)
            af[i] = *(const short8*)&sm[w * 2560 + (i * 16 + ln15) * 40 + kg * 8];
        #pragma unroll
        for (int j = 0; j < 4; ++j)
            bf[j] = *(const short8*)&sm[20480 + w * 2560 + (j * 16 + ln15) * 40 + kg * 8];
        #pragma unroll
        for (int i = 0; i < 4; ++i)
            #pragma unroll
            for (int j = 0; j < 4; ++j)
                acc[i][j] = __builtin_amdgcn_mfma_f32_16x16x32_bf16(af[i], bf[j], acc[i][j], 0, 0, 0);
        __syncthreads();
    }
    #pragma unroll
    for (int i = 0; i < 4; ++i)
        #pragma unroll
        for (int j = 0; j < 4; ++j)
            #pragma unroll
            for (int q = 0; q < 4; ++q) {
                int n = i * 16 + kg * 4 + q;
                int c = j * 16 + ln15;
                sm[(n * 64 + c) * 8 + w] = f2bf(acc[i][j][q]);
            }
    __syncthreads();
    #pragma unroll
    for (int p = 0; p < 8; ++p) {
        int u = p * 512 + t;
        int n = u >> 6;
        int c = u & 63;
        short8 x = *(const short8*)&sm[(n * 64 + c) * 8];
        size_t kb = (size_t)(b * N_ + n0 + n) * 2 + ch;
        *(short8*)(t2base + kb * 16384 + (size_t)((c >> 4) * 16 + dc) * 128 + (c & 15) * 8) = x;
    }
}

// ---------------- K2w4: R11 structure (8 iters) + XCD-pinned bid mapping ------
// Block = one (b,n), b = bid&7 (same XCD as k1's T2 writer). Weights in regs,
// A-tile in 2x12KB LDS, dbuf (T14) + swizzle. rt order {2,3,1,0,6,7,5,4}.
__global__ __launch_bounds__(512, 4) void k2_vnew_w(
        const float* __restrict__ s, const float* __restrict__ v,
        const float* __restrict__ gs, const float* __restrict__ gv,
        const unsigned short* __restrict__ wfrag,
        float* __restrict__ vnew, float* __restrict__ svv) {
    __shared__ unsigned short lds_a[2][6144];
    int t = threadIdx.x;
    int bid = blockIdx.x;
    int b = bid & 7;
    int n = bid >> 3;
    int kb2 = b * 256 + n;
    int w = t >> 6, lane = t & 63, ln15 = lane & 15, kgrp = lane >> 4;
    int ct = w;

    f32x4 wreg[12];
    #pragma unroll
    for (int kk = 0; kk < 12; ++kk)
        wreg[kk] = *(const f32x4*)&wfrag[(((ct * 12 + kk) * 4 + kgrp) * 16 + ln15) * 8];
    asm volatile("" : "+v"(wreg[0]), "+v"(wreg[1]), "+v"(wreg[2]), "+v"(wreg[3]),
                      "+v"(wreg[4]), "+v"(wreg[5]), "+v"(wreg[6]), "+v"(wreg[7]),
                      "+v"(wreg[8]), "+v"(wreg[9]), "+v"(wreg[10]), "+v"(wreg[11]));

    int r_s = t >> 5;
    int q5 = t & 31;
    int dd0 = q5 * 4;
    int kgq = (q5 >> 1) & 3;
    int lw = (q5 >> 3) * 512 + kgq * 128 + ((r_s ^ kgq) * 8) + (q5 & 1) * 4;
    int st2 = (t * 8) ^ (((t >> 4) & 3) << 3);

    float4 s4  = *(const float4*)(s + (size_t)kb2 * 128 + dd0);
    float4 gs4 = *(const float4*)(gs + (size_t)b * 128 + dd0);
    const float* gvb = gv + (size_t)b * 16384;
    const unsigned short* t2u = (const unsigned short*)(vnew + (size_t)kb2 * 16384);
    float* outp = vnew + (size_t)kb2 * 16384;

    short8 t2r;
    float4 g4, v4;
    float psum = 0.f;

    {   // prologue: rt=2
        int rt = 2;
        int crow = (rt >> 2) * 64 + (rt & 3) * 16;
        if (t < 256) t2r = *(const short8*)(t2u + (rt >> 2) * 16384 + (rt & 3) * 2048 + t * 8);
        g4 = *(const float4*)(gvb + (size_t)(crow + r_s) * 128 + dd0);
        v4 = *(const float4*)(v + ((size_t)kb2 * 128 + crow + r_s) * 128 + dd0);
        if (t < 256) *(short8*)&lds_a[0][st2] = t2r;
        uint2 p1 = make_uint2(pkhu(s4.x * g4.x, s4.y * g4.y), pkhu(s4.z * g4.z, s4.w * g4.w));
        *(uint2*)&lds_a[0][2048 + lw] = p1;
        uint2 p2 = make_uint2(pkhu(gs4.x * v4.x, gs4.y * v4.y), pkhu(gs4.z * v4.z, gs4.w * v4.w));
        *(uint2*)&lds_a[0][4096 + lw] = p2;
    }
    __syncthreads();

    #pragma unroll
    for (int j = 0; j < 8; ++j) {
        int rt = (0x45760132u >> (4 * j)) & 7;       // {2,3,1,0,6,7,5,4}
        int cur = j & 1;
        if (j < 7) {
            int rtn = (0x45760132u >> (4 * (j + 1))) & 7;
            int crn = (rtn >> 2) * 64 + (rtn & 3) * 16;
            if (t < 256) t2r = *(const short8*)(t2u + (rtn >> 2) * 16384 + (rtn & 3) * 2048 + t * 8);
            g4 = *(const float4*)(gvb + (size_t)(crn + r_s) * 128 + dd0);
            v4 = *(const float4*)(v + ((size_t)kb2 * 128 + crn + r_s) * 128 + dd0);
        }
        f32x4 acc = {0.f, 0.f, 0.f, 0.f};
        #pragma unroll
        for (int kk = 0; kk < 12; ++kk) {
            short8 a = *(const short8*)&lds_a[cur][kk * 512 + kgrp * 128 + ((ln15 ^ kgrp) * 8)];
            acc = __builtin_amdgcn_mfma_f32_16x16x32_bf16(
                a, __builtin_bit_cast(short8, wreg[kk]), acc, 0, 0, 0);
        }
        int crow = (rt >> 2) * 64 + (rt & 3) * 16;
        int e = ct * 16 + ln15;
        #pragma unroll
        for (int q = 0; q < 4; ++q) {
            int row = crow + kgrp * 4 + q;
            outp[(size_t)row * 128 + e] = acc[q];
            psum = fmaf(gvb[(size_t)row * 128 + e], acc[q], psum);
        }
        if (j < 7) {
            __syncthreads();
            if (t < 256) *(short8*)&lds_a[cur ^ 1][st2] = t2r;
            uint2 p1 = make_uint2(pkhu(s4.x * g4.x, s4.y * g4.y), pkhu(s4.z * g4.z, s4.w * g4.w));
            *(uint2*)&lds_a[cur ^ 1][2048 + lw] = p1;
            uint2 p2 = make_uint2(pkhu(gs4.x * v4.x, gs4.y * v4.y),
                                  pkhu(gs4.z * v4.z, gs4.w * v4.w));
            *(uint2*)&lds_a[cur ^ 1][4096 + lw] = p2;
            __syncthreads();
        }
    }
    psum += __shfl_xor(psum, 16);
    psum += __shfl_xor(psum, 32);
    if (kgrp == 0) svv[(size_t)kb2 * 128 + ct * 16 + ln15] = psum;
}

// ---------------- K4: s-path linears + products + MLP -------------------------
__global__ __launch_bounds__(256) void k4_spath(
        const float* __restrict__ s, const float* __restrict__ svv,
        const float* __restrict__ g1,
        const float* __restrict__ wT2, const float* __restrict__ lin2_b,
        const float* __restrict__ wT3, const float* __restrict__ lin3_b,
        const float* __restrict__ wTm1, const float* __restrict__ mlp_b1,
        const float* __restrict__ wTm2, const float* __restrict__ mlp_b2,
        float* __restrict__ sout) {
    __shared__ float xs[8][128], xv[8][128], pre[8][128], hbuf[8][128];
    int t = threadIdx.x;
    int rowb = blockIdx.x * 8;
    int b = rowb >> 8;
    #pragma unroll
    for (int i = 0; i < 4; ++i) {
        int vi = i * 256 + t;
        int r = vi >> 7, dd = vi & 127;
        xs[r][dd] = s[(size_t)(rowb + r) * 128 + dd];
        xv[r][dd] = svv[(size_t)(rowb + r) * 128 + dd];
    }
    __syncthreads();
    int e = t & 127, h2 = t >> 7;
    float b2 = lin2_b[e], b3 = lin3_b[e], g1v = g1[b * 128 + e];
    float a2[4] = {b2, b2, b2, b2}, a3[4] = {b3, b3, b3, b3};
    for (int dd = 0; dd < 128; ++dd) {
        float w2 = wT2[dd * 128 + e], w3 = wT3[dd * 128 + e];
        #pragma unroll
        for (int r = 0; r < 4; ++r) {
            a2[r] = fmaf(xs[h2 * 4 + r][dd], w2, a2[r]);
            a3[r] = fmaf(xv[h2 * 4 + r][dd], w3, a3[r]);
        }
    }
    #pragma unroll
    for (int r = 0; r < 4; ++r) pre[h2 * 4 + r][e] = g1v * a2[r] * a3[r];
    __syncthreads();
    float bm1 = mlp_b1[e];
    float ah[4] = {bm1, bm1, bm1, bm1};
    for (int dd = 0; dd < 128; ++dd) {
        float w = wTm1[dd * 128 + e];
        #pragma unroll
        for (int r = 0; r < 4; ++r) ah[r] = fmaf(pre[h2 * 4 + r][dd], w, ah[r]);
    }
    #pragma unroll
    for (int r = 0; r < 4; ++r) hbuf[h2 * 4 + r][e] = fmaxf(ah[r], 0.f);
    __syncthreads();
    float bm2 = mlp_b2[e];
    float ao[4] = {bm2, bm2, bm2, bm2};
    for (int dd = 0; dd < 128; ++dd) {
        float w = wTm2[dd * 128 + e];
        #pragma unroll
        for (int r = 0; r < 4; ++r) ao[r] = fmaf(hbuf[h2 * 4 + r][dd], w, ao[r]);
    }
    #pragma unroll
    for (int r = 0; r < 4; ++r) sout[(size_t)(rowb + h2 * 4 + r) * 128 + e] = ao[r];
}

extern "C" void kernel_launch(void* const* d_in, const int* in_sizes, int n_in,
                              void* d_out, int out_size, void* d_ws, size_t ws_size,
                              hipStream_t stream) {
    const float* s       = (const float*)d_in[0];
    const float* v       = (const float*)d_in[1];
    const float* gs      = (const float*)d_in[2];
    const float* gv      = (const float*)d_in[3];
    const float* gv2     = (const float*)d_in[4];
    const float* lin1_w  = (const float*)d_in[5];
    const float* lin1_b  = (const float*)d_in[6];
    const float* lin2_w  = (const float*)d_in[7];
    const float* lin2_b  = (const float*)d_in[8];
    const float* lin3_w  = (const float*)d_in[9];
    const float* lin3_b  = (const float*)d_in[10];
    const float* linv1_w = (const float*)d_in[11];
    const float* linv2_w = (const float*)d_in[12];
    const float* linv3_w = (const float*)d_in[13];
    const float* mlp_w1  = (const float*)d_in[14];
    const float* mlp_b1  = (const float*)d_in[15];
    const float* mlp_w2  = (const float*)d_in[16];
    const float* mlp_b2  = (const float*)d_in[17];

    float* sout = (float*)d_out;
    float* vnew = (float*)d_out + 262144;   // v_new region; doubles as T2 (bf16)

    float* wsf   = (float*)d_ws;
    float* wT2   = wsf;
    float* wT3   = wsf + 16384;
    float* wTm1  = wsf + 32768;
    float* wTm2  = wsf + 49152;
    float* s_v2t = wsf + 65536;
    float* g1    = wsf + 66560;
    float* svv   = wsf + 67584;
    unsigned short* wfrag = (unsigned short*)(wsf + 329728);           // 96 KB
    unsigned short* vT  = (unsigned short*)((char*)d_ws + 2097152);    // 67.1 MB
    unsigned short* gT  = (unsigned short*)((char*)d_ws + 69206016);   // 33.5 MB
    bool big = ws_size >= 102760448ULL;

    if (big) {
        kt_all<<<3528, 256, 0, stream>>>(v, gv2, lin2_w, lin3_w, mlp_w1, mlp_w2,
                                         linv1_w, linv2_w, linv3_w, vT, gT,
                                         wT2, wT3, wTm1, wTm2, wfrag, s_v2t);
        k0c_g1<<<8, 128, 0, stream>>>(s_v2t, lin1_w, lin1_b, gs, g1);
        k1_T2_fast<<<1024, 512, 0, stream>>>(vT, gT, (unsigned short*)vnew);
    } else {
        kt_all<<<3528, 256, 0, stream>>>(v, gv2, lin2_w, lin3_w, mlp_w1, mlp_w2,
                                         linv1_w, linv2_w, linv3_w,
                                         (unsigned short*)(wsf + 200000),
                                         (unsigned short*)(wsf + 200000),
                                         wT2, wT3, wTm1, wTm2, wfrag, s_v2t);
        k0c_g1<<<8, 128, 0, stream>>>(s_v2t, lin1_w, lin1_b, gs, g1);
        k1_T2_legacy<<<1024, 512, 0, stream>>>(v, gv2, (unsigned short*)vnew);
    }
    k2_vnew_w<<<2048, 512, 0, stream>>>(s, v, gs, gv, wfrag, vnew, svv);
    k4_spath<<<256, 256, 0, stream>>>(s, svv, g1, wT2, lin2_b, wT3, lin3_b,
                                      wTm1, mlp_b1, wTm2, mlp_b2, sout);
}